// Round 9
// baseline (205.878 us; speedup 1.0000x reference)
//
#include <hip/hip_runtime.h>
#include <math.h>

#define BS 2
#define C_DIM 256
#define N_DIM 4096
#define E_DIM 2048
#define P_DIM 32
#define NS1 32   // n-splits for proto1
#define FS2 8    // f-splits for proto2

typedef __attribute__((ext_vector_type(8))) short short8;
typedef __attribute__((ext_vector_type(4))) float f32x4;

__device__ __forceinline__ unsigned short f2bf(float f) {
  unsigned u = __float_as_uint(f);
  return (unsigned short)((u + 0x7FFFu + ((u >> 16) & 1u)) >> 16);
}

// ---------------------------------------------------------------------------
// A: K[b][n][p] = BN(proj_w @ vf), Ksq[b][n] = sum_p K^2.  grid 128, block 256
// ---------------------------------------------------------------------------
__global__ __launch_bounds__(256) void k_proj(
    const float* __restrict__ vf, const float* __restrict__ pw,
    const float* __restrict__ gamma, const float* __restrict__ beta,
    const float* __restrict__ mean, const float* __restrict__ var,
    float* __restrict__ Kf, float* __restrict__ Ksq) {
  __shared__ float w_s[P_DIM * C_DIM];
  __shared__ float part_s[4][64][P_DIM + 1];
  __shared__ float kt_s[64][P_DIM + 1];
  __shared__ float sc_s[P_DIM], sb_s[P_DIM], sm_s[P_DIM];

  const int tid = threadIdx.x;
  const int b = blockIdx.x >> 6;
  const int n0 = (blockIdx.x & 63) << 6;

  for (int i = tid; i < P_DIM * C_DIM; i += 256) w_s[i] = pw[i];
  if (tid < P_DIM) {
    sc_s[tid] = gamma[tid] / sqrtf(var[tid] + 1e-5f);
    sb_s[tid] = beta[tid];
    sm_s[tid] = mean[tid];
  }
  __syncthreads();

  const int nl = tid & 63, cs = tid >> 6;
  const float* vbase = vf + (size_t)b * C_DIM * N_DIM + n0 + nl;
  float acc[P_DIM];
#pragma unroll
  for (int p = 0; p < P_DIM; ++p) acc[p] = 0.f;
#pragma unroll 4
  for (int cc = 0; cc < 64; ++cc) {
    int c = cs * 64 + cc;
    float v = vbase[(size_t)c * N_DIM];
    const float* wc = &w_s[c];
#pragma unroll
    for (int p = 0; p < P_DIM; ++p) acc[p] = fmaf(wc[p * C_DIM], v, acc[p]);
  }
#pragma unroll
  for (int p = 0; p < P_DIM; ++p) part_s[cs][nl][p] = acc[p];
  __syncthreads();

  for (int i = tid; i < 64 * P_DIM; i += 256) {
    int n_l = i >> 5, p = i & 31;
    float s = ((part_s[0][n_l][p] + part_s[1][n_l][p]) + part_s[2][n_l][p]) +
              part_s[3][n_l][p];
    float k = (s - sm_s[p]) * sc_s[p] + sb_s[p];
    Kf[((size_t)(b * N_DIM + n0 + n_l)) * P_DIM + p] = k;
    kt_s[n_l][p] = k;
  }
  __syncthreads();
  if (tid < 64) {
    float q = 0.f;
#pragma unroll
    for (int p = 0; p < P_DIM; ++p) q = fmaf(kt_s[tid][p], kt_s[tid][p], q);
    Ksq[b * N_DIM + n0 + tid] = q;
  }
}

// ---------------------------------------------------------------------------
// A2: VT[b][n][c] = vf[b][c][n].  grid 512, block 256
// ---------------------------------------------------------------------------
__global__ __launch_bounds__(256) void k_transpose(const float* __restrict__ vf,
                                                   float* __restrict__ VT) {
  __shared__ float t_s[64][65];
  const int tid = threadIdx.x;
  const int b = blockIdx.x >> 8;
  const int n0 = ((blockIdx.x >> 2) & 63) << 6;
  const int c0 = (blockIdx.x & 3) << 6;
  const float* src = vf + (size_t)b * C_DIM * N_DIM;
#pragma unroll
  for (int i = 0; i < 16; ++i) {
    int idx = tid + i * 256;
    int n_l = idx & 63, c_l = idx >> 6;
    t_s[c_l][n_l] = src[(size_t)(c0 + c_l) * N_DIM + n0 + n_l];
  }
  __syncthreads();
  float* dst = VT + (size_t)b * N_DIM * C_DIM;
#pragma unroll
  for (int i = 0; i < 16; ++i) {
    int idx = tid + i * 256;
    int c_l = idx & 63, n_l = idx >> 6;
    dst[(size_t)(n0 + n_l) * C_DIM + c0 + c_l] = t_s[c_l][n_l];
  }
}

// ---------------------------------------------------------------------------
// B1: P1part[ns][b][e][p] = sum_{n in 128-chunk} inc[b][n][e]*K[b][n][p]
// grid 256 (= bs * 4 etiles(512e) * 32 nsplits), block 256, 2 e per thread.
// ---------------------------------------------------------------------------
__global__ __launch_bounds__(256) void k_proto1(const float* __restrict__ inc,
                                                const float* __restrict__ Kf,
                                                float* __restrict__ part) {
  __shared__ float k_s[64][P_DIM];
  const int tid = threadIdx.x;
  const int b = blockIdx.x >> 7;
  const int et = (blockIdx.x >> 5) & 3;
  const int ns = blockIdx.x & 31;
  const int e0 = et << 9;
  const int nbase = ns << 7;

  float acc0[P_DIM], acc1[P_DIM];
#pragma unroll
  for (int p = 0; p < P_DIM; ++p) { acc0[p] = 0.f; acc1[p] = 0.f; }

  for (int nt = 0; nt < 2; ++nt) {
    int n0 = nbase + nt * 64;
#pragma unroll
    for (int i = 0; i < 8; ++i) {
      int idx = tid + i * 256;
      ((float*)k_s)[idx] = Kf[((size_t)(b * N_DIM + n0)) * P_DIM + idx];
    }
    __syncthreads();
#pragma unroll 8
    for (int nn = 0; nn < 64; ++nn) {
      const float* irow = inc + ((size_t)(b * N_DIM + n0 + nn)) * E_DIM + e0;
      float va = irow[tid];
      float vb = irow[tid + 256];
      const float4* kv4 = (const float4*)k_s[nn];
#pragma unroll
      for (int q = 0; q < 8; ++q) {
        float4 kv = kv4[q];
        acc0[4 * q + 0] = fmaf(va, kv.x, acc0[4 * q + 0]);
        acc0[4 * q + 1] = fmaf(va, kv.y, acc0[4 * q + 1]);
        acc0[4 * q + 2] = fmaf(va, kv.z, acc0[4 * q + 2]);
        acc0[4 * q + 3] = fmaf(va, kv.w, acc0[4 * q + 3]);
        acc1[4 * q + 0] = fmaf(vb, kv.x, acc1[4 * q + 0]);
        acc1[4 * q + 1] = fmaf(vb, kv.y, acc1[4 * q + 1]);
        acc1[4 * q + 2] = fmaf(vb, kv.z, acc1[4 * q + 2]);
        acc1[4 * q + 3] = fmaf(vb, kv.w, acc1[4 * q + 3]);
      }
    }
    __syncthreads();
  }
  float* dst0 = part + (size_t)ns * (BS * E_DIM * P_DIM) +
                ((size_t)(b * E_DIM + e0 + tid)) * P_DIM;
  float* dst1 = dst0 + 256 * P_DIM;
#pragma unroll
  for (int q = 0; q < 8; ++q) {
    ((float4*)dst0)[q] = make_float4(acc0[4 * q + 0], acc0[4 * q + 1],
                                     acc0[4 * q + 2], acc0[4 * q + 3]);
    ((float4*)dst1)[q] = make_float4(acc1[4 * q + 0], acc1[4 * q + 1],
                                     acc1[4 * q + 2], acc1[4 * q + 3]);
  }
}

// ---------------------------------------------------------------------------
// B2: proto1 = sum of 32 partials.  grid 512, block 256
// ---------------------------------------------------------------------------
__global__ __launch_bounds__(256) void k_red32(const float* __restrict__ part,
                                               float* __restrict__ outp) {
  int g = blockIdx.x * 256 + threadIdx.x;
  float v = 0.f;
#pragma unroll
  for (int s = 0; s < NS1; ++s)
    v += part[(size_t)s * (BS * E_DIM * P_DIM) + g];
  outp[g] = v;
}

// ---------------------------------------------------------------------------
// B3: P2part[fs][b][e][p] = sum_{f in 256-chunk} ied[b][e][f]*proto1[b][f][p]
// grid 256, block 256, [2e][8p]/thread. ALSO emits ied_h = bf16(ied).
// ---------------------------------------------------------------------------
__global__ __launch_bounds__(256) void k_proto2(const float* __restrict__ ied,
                                                const float* __restrict__ proto1,
                                                float* __restrict__ part,
                                                short* __restrict__ ied_h) {
  __shared__ float inv_s[128][33];
  __shared__ float p1_s[32][P_DIM];
  const int tid = threadIdx.x;
  const int b = blockIdx.x >> 7;
  const int et = (blockIdx.x >> 3) & 15;
  const int fs = blockIdx.x & 7;
  const int e0 = et << 7;
  const int fbase = fs << 8;
  const int e_l = tid & 63, pg = tid >> 6;

  float acc0[8], acc1[8];
#pragma unroll
  for (int q = 0; q < 8; ++q) { acc0[q] = 0.f; acc1[q] = 0.f; }

  for (int ft = 0; ft < 8; ++ft) {
    int f0 = fbase + ft * 32;
    __syncthreads();
#pragma unroll
    for (int i = 0; i < 16; ++i) {
      int idx = tid + i * 256;
      int e_r = idx >> 5, f_l = idx & 31;
      size_t gidx = ((size_t)(b * E_DIM + e0 + e_r)) * E_DIM + f0 + f_l;
      float v = ied[gidx];
      inv_s[e_r][f_l] = v;
      ied_h[gidx] = (short)f2bf(v);
    }
#pragma unroll
    for (int i = 0; i < 4; ++i) {
      int idx = tid + i * 256;
      ((float*)p1_s)[idx] = proto1[((size_t)(b * E_DIM + f0)) * P_DIM + idx];
    }
    __syncthreads();
#pragma unroll
    for (int ff = 0; ff < 32; ++ff) {
      float a0 = inv_s[e_l][ff];
      float a1 = inv_s[e_l + 64][ff];
      const float4* pv4 = (const float4*)&p1_s[ff][pg * 8];
      float4 pv0 = pv4[0], pv1 = pv4[1];
      acc0[0] = fmaf(a0, pv0.x, acc0[0]);
      acc0[1] = fmaf(a0, pv0.y, acc0[1]);
      acc0[2] = fmaf(a0, pv0.z, acc0[2]);
      acc0[3] = fmaf(a0, pv0.w, acc0[3]);
      acc0[4] = fmaf(a0, pv1.x, acc0[4]);
      acc0[5] = fmaf(a0, pv1.y, acc0[5]);
      acc0[6] = fmaf(a0, pv1.z, acc0[6]);
      acc0[7] = fmaf(a0, pv1.w, acc0[7]);
      acc1[0] = fmaf(a1, pv0.x, acc1[0]);
      acc1[1] = fmaf(a1, pv0.y, acc1[1]);
      acc1[2] = fmaf(a1, pv0.z, acc1[2]);
      acc1[3] = fmaf(a1, pv0.w, acc1[3]);
      acc1[4] = fmaf(a1, pv1.x, acc1[4]);
      acc1[5] = fmaf(a1, pv1.y, acc1[5]);
      acc1[6] = fmaf(a1, pv1.z, acc1[6]);
      acc1[7] = fmaf(a1, pv1.w, acc1[7]);
    }
  }
  float* dst0 = part + (size_t)fs * (BS * E_DIM * P_DIM) +
                ((size_t)(b * E_DIM + e0 + e_l)) * P_DIM + pg * 8;
  float* dst1 = dst0 + 64 * P_DIM;
  ((float4*)dst0)[0] = make_float4(acc0[0], acc0[1], acc0[2], acc0[3]);
  ((float4*)dst0)[1] = make_float4(acc0[4], acc0[5], acc0[6], acc0[7]);
  ((float4*)dst1)[0] = make_float4(acc1[0], acc1[1], acc1[2], acc1[3]);
  ((float4*)dst1)[1] = make_float4(acc1[4], acc1[5], acc1[6], acc1[7]);
}

// ---------------------------------------------------------------------------
// B4: proto = sum of 8 partials; proto_sq = rownorm^2.  grid 512, block 256
// ---------------------------------------------------------------------------
__global__ __launch_bounds__(256) void k_red8sq(const float* __restrict__ part,
                                                float* __restrict__ proto,
                                                float* __restrict__ psq) {
  int g = blockIdx.x * 256 + threadIdx.x;
  float v = 0.f;
#pragma unroll
  for (int s = 0; s < FS2; ++s)
    v += part[(size_t)s * (BS * E_DIM * P_DIM) + g];
  proto[g] = v;
  float q = v * v;
#pragma unroll
  for (int m = 1; m <= 16; m <<= 1) q += __shfl_xor(q, m, 64);
  if ((threadIdx.x & 31) == 0) psq[g >> 5] = q;
}

// ---------------------------------------------------------------------------
// C1: per-(edge, 128-n-chunk) max of g = 2*<proto_e,K_n> - Ksq_n
// grid 2048 (= bs * 32 etiles(64e) * 32 chunks), block 256 (4 waves).
// One chunk per block; 64e x 128n tile; 4e x 8n microtile, 8 named float4
// accumulators (static indexing only — no spill). fmaf chain per (e,n)
// identical to R3 version; max reordering is exact -> chunkg bitwise same.
// ---------------------------------------------------------------------------
__global__ __launch_bounds__(256) void k_gmax(const float* __restrict__ Kf,
                                              const float* __restrict__ Ksq,
                                              const float* __restrict__ proto,
                                              float* __restrict__ chunkg) {
  __shared__ float a_s[P_DIM][64];   // [p][e]
  __shared__ float b_s[P_DIM][128];  // [p][n]
  __shared__ float q_s[128];
  const int tid = threadIdx.x;
  const int b = blockIdx.x >> 10;
  const int et = (blockIdx.x >> 5) & 31;
  const int ch = blockIdx.x & 31;
  const int e0 = et << 6;
  const int n0 = ch << 7;

#pragma unroll
  for (int i = 0; i < 8; ++i) {
    int idx = tid + i * 256;
    int e = idx >> 5, p = idx & 31;
    a_s[p][e] = proto[((size_t)(b * E_DIM + e0 + e)) * P_DIM + p];
  }
#pragma unroll
  for (int i = 0; i < 16; ++i) {
    int idx = tid + i * 256;
    int n = idx >> 5, p = idx & 31;
    b_s[p][n] = Kf[((size_t)(b * N_DIM + n0 + n)) * P_DIM + p];
  }
  if (tid < 128) q_s[tid] = Ksq[b * N_DIM + n0 + tid];
  __syncthreads();

  const int te = tid >> 4, j = tid & 15;  // te: 4-e group, j: 8-n group
  f32x4 z = {0.f, 0.f, 0.f, 0.f};
  f32x4 a0a = z, a0b = z, a1a = z, a1b = z;
  f32x4 a2a = z, a2b = z, a3a = z, a3b = z;

#pragma unroll
  for (int p = 0; p < P_DIM; ++p) {
    float4 av = *(const float4*)&a_s[p][te << 2];
    float4 b0 = *(const float4*)&b_s[p][j << 3];
    float4 b1 = *(const float4*)&b_s[p][(j << 3) + 4];
    a0a.x = fmaf(av.x, b0.x, a0a.x); a0a.y = fmaf(av.x, b0.y, a0a.y);
    a0a.z = fmaf(av.x, b0.z, a0a.z); a0a.w = fmaf(av.x, b0.w, a0a.w);
    a0b.x = fmaf(av.x, b1.x, a0b.x); a0b.y = fmaf(av.x, b1.y, a0b.y);
    a0b.z = fmaf(av.x, b1.z, a0b.z); a0b.w = fmaf(av.x, b1.w, a0b.w);
    a1a.x = fmaf(av.y, b0.x, a1a.x); a1a.y = fmaf(av.y, b0.y, a1a.y);
    a1a.z = fmaf(av.y, b0.z, a1a.z); a1a.w = fmaf(av.y, b0.w, a1a.w);
    a1b.x = fmaf(av.y, b1.x, a1b.x); a1b.y = fmaf(av.y, b1.y, a1b.y);
    a1b.z = fmaf(av.y, b1.z, a1b.z); a1b.w = fmaf(av.y, b1.w, a1b.w);
    a2a.x = fmaf(av.z, b0.x, a2a.x); a2a.y = fmaf(av.z, b0.y, a2a.y);
    a2a.z = fmaf(av.z, b0.z, a2a.z); a2a.w = fmaf(av.z, b0.w, a2a.w);
    a2b.x = fmaf(av.z, b1.x, a2b.x); a2b.y = fmaf(av.z, b1.y, a2b.y);
    a2b.z = fmaf(av.z, b1.z, a2b.z); a2b.w = fmaf(av.z, b1.w, a2b.w);
    a3a.x = fmaf(av.w, b0.x, a3a.x); a3a.y = fmaf(av.w, b0.y, a3a.y);
    a3a.z = fmaf(av.w, b0.z, a3a.z); a3a.w = fmaf(av.w, b0.w, a3a.w);
    a3b.x = fmaf(av.w, b1.x, a3b.x); a3b.y = fmaf(av.w, b1.y, a3b.y);
    a3b.z = fmaf(av.w, b1.z, a3b.z); a3b.w = fmaf(av.w, b1.w, a3b.w);
  }

  const int qb = j << 3;
  float q0 = q_s[qb + 0], q1 = q_s[qb + 1], q2 = q_s[qb + 2], q3 = q_s[qb + 3];
  float q4 = q_s[qb + 4], q5 = q_s[qb + 5], q6 = q_s[qb + 6], q7 = q_s[qb + 7];

#pragma unroll
  for (int r = 0; r < 4; ++r) {
    f32x4 pa = (r == 0) ? a0a : (r == 1) ? a1a : (r == 2) ? a2a : a3a;
    f32x4 pb = (r == 0) ? a0b : (r == 1) ? a1b : (r == 2) ? a2b : a3b;
    float m = fmaf(2.0f, pa.x, -q0);
    m = fmaxf(m, fmaf(2.0f, pa.y, -q1));
    m = fmaxf(m, fmaf(2.0f, pa.z, -q2));
    m = fmaxf(m, fmaf(2.0f, pa.w, -q3));
    m = fmaxf(m, fmaf(2.0f, pb.x, -q4));
    m = fmaxf(m, fmaf(2.0f, pb.y, -q5));
    m = fmaxf(m, fmaf(2.0f, pb.z, -q6));
    m = fmaxf(m, fmaf(2.0f, pb.w, -q7));
    m = fmaxf(m, __shfl_xor(m, 1, 64));
    m = fmaxf(m, __shfl_xor(m, 2, 64));
    m = fmaxf(m, __shfl_xor(m, 4, 64));
    m = fmaxf(m, __shfl_xor(m, 8, 64));
    if (j == 0)
      chunkg[((size_t)(b * E_DIM + e0 + (te << 2) + r)) * 32 + ch] = m;
  }
}

// ---------------------------------------------------------------------------
// C2: per-edge sparse softmax-aggregate. One wave per edge.
// grid 1024, block 256 (4 waves).
// ---------------------------------------------------------------------------
__device__ __forceinline__ float edge_logit(const float* __restrict__ Kb,
                                            const float* __restrict__ Qb,
                                            const float* pr, float psqv,
                                            int n) {
  const float4* kp = (const float4*)(Kb + (size_t)n * P_DIM);
  float i0 = 0.f, i1 = 0.f, i2 = 0.f, i3 = 0.f;
#pragma unroll
  for (int q = 0; q < 8; ++q) {
    float4 kv = kp[q];
    i0 = fmaf(pr[4 * q + 0], kv.x, i0);
    i1 = fmaf(pr[4 * q + 1], kv.y, i1);
    i2 = fmaf(pr[4 * q + 2], kv.z, i2);
    i3 = fmaf(pr[4 * q + 3], kv.w, i3);
  }
  float inner = (i0 + i1) + (i2 + i3);
  float cost = fmaf(-2.0f, inner, psqv + Qb[n]);
  const float tau_eps = 0.1f + 1e-8f;
  return (-cost) / tau_eps;
}

__global__ __launch_bounds__(256) void k_sparse(
    const float* __restrict__ Kf, const float* __restrict__ Ksq,
    const float* __restrict__ proto, const float* __restrict__ psq,
    const float* __restrict__ VT, const float* __restrict__ chunkg,
    float* __restrict__ EF0) {
  const int tid = threadIdx.x;
  const int lane = tid & 63;
  const int eg = blockIdx.x * 4 + (tid >> 6);
  const int b = eg >> 11;
  const float* Kb = Kf + (size_t)b * N_DIM * P_DIM;
  const float* Qb = Ksq + (size_t)b * N_DIM;

  float cg = (lane < 32) ? chunkg[(size_t)eg * 32 + lane] : -INFINITY;
  float gmax = cg;
#pragma unroll
  for (int m = 1; m <= 32; m <<= 1) gmax = fmaxf(gmax, __shfl_xor(gmax, m, 64));
  unsigned long long live = __ballot(cg > gmax - 20.0f);

  float pr[P_DIM];
  const float* pe = proto + (size_t)eg * P_DIM;
#pragma unroll
  for (int p = 0; p < P_DIM; ++p) pr[p] = pe[p];
  const float psqv = psq[eg];

  float L = -INFINITY;
  unsigned long long m0 = live;
  while (m0) {
    int c = __ffsll(m0) - 1;
    m0 &= m0 - 1;
    int n = (c << 7) + lane;
    L = fmaxf(L, edge_logit(Kb, Qb, pr, psqv, n));
    L = fmaxf(L, edge_logit(Kb, Qb, pr, psqv, n + 64));
  }
#pragma unroll
  for (int m = 1; m <= 32; m <<= 1) L = fmaxf(L, __shfl_xor(L, m, 64));

  float4 acc = make_float4(0.f, 0.f, 0.f, 0.f);
  float sw = 0.f;
  const float* Vb = VT + (size_t)b * N_DIM * C_DIM;
  m0 = live;
  while (m0) {
    int c = __ffsll(m0) - 1;
    m0 &= m0 - 1;
#pragma unroll
    for (int h = 0; h < 2; ++h) {
      int n = (c << 7) + (h << 6) + lane;
      float l = edge_logit(Kb, Qb, pr, psqv, n);
      float d = l - L;
      float wgt = (d > -25.0f) ? expf(d) : 0.f;
      sw += wgt;
      unsigned long long hits = __ballot(wgt > 0.f);
      while (hits) {
        int src = __ffsll(hits) - 1;
        hits &= hits - 1;
        float wv = __shfl(wgt, src, 64);
        int nv = (c << 7) + (h << 6) + src;
        const float4 vrow =
            *(const float4*)(Vb + (size_t)nv * C_DIM + (lane << 2));
        acc.x = fmaf(wv, vrow.x, acc.x);
        acc.y = fmaf(wv, vrow.y, acc.y);
        acc.z = fmaf(wv, vrow.z, acc.z);
        acc.w = fmaf(wv, vrow.w, acc.w);
      }
    }
  }
#pragma unroll
  for (int m = 1; m <= 32; m <<= 1) sw += __shfl_xor(sw, m, 64);

  float* dst = EF0 + (size_t)eg * C_DIM + (lane << 2);
  *(float4*)dst =
      make_float4(acc.x / sw, acc.y / sw, acc.z / sw, acc.w / sw);
}

// ---------------------------------------------------------------------------
// C3: EF0t[b][c][f] = bf16(EF0[b][f][c]).  grid 256, block 256, 64x64 tiles
// ---------------------------------------------------------------------------
__global__ __launch_bounds__(256) void k_ef0t(const float* __restrict__ EF0,
                                              short* __restrict__ EF0t) {
  __shared__ short sh[64][72];
  const int tid = threadIdx.x;
  const int b = blockIdx.x >> 7;
  const int ft = (blockIdx.x >> 2) & 31;
  const int ct = blockIdx.x & 3;
  const int f0 = ft << 6, c0 = ct << 6;
#pragma unroll
  for (int i = 0; i < 4; ++i) {
    int idx = tid + i * 256;
    int f_l = idx >> 4, cc = idx & 15;
    float4 v =
        *(const float4*)&EF0[((size_t)(b * E_DIM + f0 + f_l)) * C_DIM + c0 +
                             cc * 4];
    sh[cc * 4 + 0][f_l] = (short)f2bf(v.x);
    sh[cc * 4 + 1][f_l] = (short)f2bf(v.y);
    sh[cc * 4 + 2][f_l] = (short)f2bf(v.z);
    sh[cc * 4 + 3][f_l] = (short)f2bf(v.w);
  }
  __syncthreads();
#pragma unroll
  for (int i = 0; i < 2; ++i) {
    int idx = tid + i * 256;
    int c_l = idx >> 3, ch = idx & 7;
    short8 v = *(const short8*)&sh[c_l][ch * 8];
    *(short8*)&EF0t[((size_t)(b * C_DIM + c0 + c_l)) * E_DIM + f0 + ch * 8] = v;
  }
}

// ---------------------------------------------------------------------------
// D: bf16 MFMA GEMM, full K (no split), double-buffered LDS + reg prefetch.
// out[b][c][e] = sum_f ied[b][e][f] * EF0[b][f][c].
// grid 256 (= 2b * 32et * 4ct), block 256 (4 waves). Tile 64e x 64c, BK=64,
// wave quad 32x32. LDS XOR-swizzle (byte ^= (row&7)<<4), 1 barrier/K-step.
// ---------------------------------------------------------------------------
__device__ __forceinline__ short8 lds_frag(const short* s, int row, int k) {
  int off = (((row << 6) + k) << 1) ^ ((row & 7) << 4);
  return *(const short8*)((const char*)s + off);
}
__device__ __forceinline__ void lds_put(short* s, int row, int k, short8 v) {
  int off = (((row << 6) + k) << 1) ^ ((row & 7) << 4);
  *(short8*)((char*)s + off) = v;
}

__global__ __launch_bounds__(256) void k_final_mfma(
    const short* __restrict__ Ah, const short* __restrict__ Bh,
    float* __restrict__ out) {
  __shared__ short As[2][64 * 64];
  __shared__ short Bs[2][64 * 64];
  __shared__ float Cs[64][68];

  const int tid = threadIdx.x;
  const int lane = tid & 63;
  const int w = tid >> 6;
  const int ct = blockIdx.x & 3;
  const int et = (blockIdx.x >> 2) & 31;
  const int b = blockIdx.x >> 7;
  const int e0 = et << 6, c0 = ct << 6;

  const int we = (w >> 1) << 5;   // wave e-quadrant offset
  const int wc = (w & 1) << 5;    // wave c-quadrant offset
  const int row = tid >> 2, ch = tid & 3;

  const short* gA = Ah + ((size_t)(b * E_DIM + e0 + row)) * E_DIM;
  const short* gB = Bh + ((size_t)(b * C_DIM + c0 + row)) * E_DIM;

  f32x4 z = {0.f, 0.f, 0.f, 0.f};
  f32x4 acc00 = z, acc01 = z, acc10 = z, acc11 = z;

  // prologue: tile 0 -> LDS[0]
  {
    const short8* pa = (const short8*)(gA + ch * 16);
    const short8* pb = (const short8*)(gB + ch * 16);
    short8 a0 = pa[0], a1 = pa[1];
    short8 b0 = pb[0], b1 = pb[1];
    lds_put(As[0], row, ch * 16, a0);
    lds_put(As[0], row, ch * 16 + 8, a1);
    lds_put(Bs[0], row, ch * 16, b0);
    lds_put(Bs[0], row, ch * 16 + 8, b1);
  }
  __syncthreads();

  for (int kt = 0; kt < 32; ++kt) {
    const int cur = kt & 1;
    short8 na0, na1, nb0, nb1;
    if (kt < 31) {  // issue next-tile loads early (hide HBM under MFMA)
      const int f1 = (kt + 1) << 6;
      const short8* pa = (const short8*)(gA + f1 + ch * 16);
      const short8* pb = (const short8*)(gB + f1 + ch * 16);
      na0 = pa[0]; na1 = pa[1]; nb0 = pb[0]; nb1 = pb[1];
    }
#pragma unroll
    for (int s = 0; s < 2; ++s) {
      const int kb = (s << 5) + ((lane >> 4) << 3);
      short8 fa0 = lds_frag(As[cur], we + (lane & 15), kb);
      short8 fa1 = lds_frag(As[cur], we + 16 + (lane & 15), kb);
      short8 fb0 = lds_frag(Bs[cur], wc + (lane & 15), kb);
      short8 fb1 = lds_frag(Bs[cur], wc + 16 + (lane & 15), kb);
      acc00 = __builtin_amdgcn_mfma_f32_16x16x32_bf16(fa0, fb0, acc00, 0, 0, 0);
      acc01 = __builtin_amdgcn_mfma_f32_16x16x32_bf16(fa0, fb1, acc01, 0, 0, 0);
      acc10 = __builtin_amdgcn_mfma_f32_16x16x32_bf16(fa1, fb0, acc10, 0, 0, 0);
      acc11 = __builtin_amdgcn_mfma_f32_16x16x32_bf16(fa1, fb1, acc11, 0, 0, 0);
    }
    if (kt < 31) {  // write into the buffer last read at kt-1 (barrier-safe)
      lds_put(As[cur ^ 1], row, ch * 16, na0);
      lds_put(As[cur ^ 1], row, ch * 16 + 8, na1);
      lds_put(Bs[cur ^ 1], row, ch * 16, nb0);
      lds_put(Bs[cur ^ 1], row, ch * 16 + 8, nb1);
    }
    __syncthreads();
  }

  // epilogue: stage transposed [c][e] in LDS, then coalesced fp32 writes
  const int fr = lane & 15, fq = lane >> 4;
#pragma unroll
  for (int r = 0; r < 4; ++r) {
    Cs[wc + fr][we + fq * 4 + r] = acc00[r];
    Cs[wc + 16 + fr][we + fq * 4 + r] = acc01[r];
    Cs[wc + fr][we + 16 + fq * 4 + r] = acc10[r];
    Cs[wc + 16 + fr][we + 16 + fq * 4 + r] = acc11[r];
  }
  __syncthreads();
  {
    const int c_l = tid >> 2, cch = tid & 3;
    float* dst = out + ((size_t)(b * C_DIM + c0 + c_l)) * E_DIM + e0;
#pragma unroll
    for (int r = 0; r < 4; ++r) {
      float4 v = *(const float4*)&Cs[c_l][cch * 16 + r * 4];
      *(float4*)&dst[cch * 16 + r * 4] = v;
    }
  }
}

// ---------------------------------------------------------------------------
extern "C" void kernel_launch(void* const* d_in, const int* in_sizes, int n_in,
                              void* d_out, int out_size, void* d_ws,
                              size_t ws_size, hipStream_t stream) {
  (void)in_sizes; (void)n_in; (void)out_size; (void)ws_size;
  const float* vf  = (const float*)d_in[0];
  const float* inc = (const float*)d_in[1];
  const float* ied = (const float*)d_in[2];
  const float* pw  = (const float*)d_in[5];
  const float* gm  = (const float*)d_in[6];
  const float* bt  = (const float*)d_in[7];
  const float* mn  = (const float*)d_in[8];
  const float* vr  = (const float*)d_in[9];
  float* out = (float*)d_out;

  float* ws = (float*)d_ws;
  float* VT      = ws;                  // 2,097,152 f
  float* Kf      = VT + 2097152;        //   262,144
  float* Ksq     = Kf + 262144;         //     8,192
  float* proto1  = Ksq + 8192;          //   131,072
  float* proto   = proto1 + 131072;     //   131,072
  float* psq     = proto + 131072;      //     4,096
  float* P1p     = psq + 4096;          // 32*131,072 = 4,194,304
  float* P2p     = P1p + 4194304;       //  8*131,072 = 1,048,576
  float* EF0     = P2p + 1048576;       // 1,048,576
  float* chunkg  = EF0 + 1048576;       //   131,072
  short* ied_h   = (short*)(chunkg + 131072);            // 8,388,608 shorts
  short* EF0t    = (short*)(chunkg + 131072 + 4194304);  // 1,048,576 shorts
  // total ~47 MB

  k_proj<<<dim3(128), dim3(256), 0, stream>>>(vf, pw, gm, bt, mn, vr, Kf, Ksq);
  k_transpose<<<dim3(512), dim3(256), 0, stream>>>(vf, VT);
  k_proto1<<<dim3(256), dim3(256), 0, stream>>>(inc, Kf, P1p);
  k_red32<<<dim3(512), dim3(256), 0, stream>>>(P1p, proto1);
  k_proto2<<<dim3(256), dim3(256), 0, stream>>>(ied, proto1, P2p, ied_h);
  k_red8sq<<<dim3(512), dim3(256), 0, stream>>>(P2p, proto, psq);
  k_gmax<<<dim3(2048), dim3(256), 0, stream>>>(Kf, Ksq, proto, chunkg);
  k_sparse<<<dim3(1024), dim3(256), 0, stream>>>(Kf, Ksq, proto, psq, VT,
                                                 chunkg, EF0);
  k_ef0t<<<dim3(256), dim3(256), 0, stream>>>(EF0, EF0t);
  k_final_mfma<<<dim3(256), dim3(256), 0, stream>>>(ied_h, EF0t, out);
}

// Round 10
// 193.018 us; speedup vs baseline: 1.0666x; 1.0666x over previous
//
#include <hip/hip_runtime.h>
#include <math.h>

#define BS 2
#define C_DIM 256
#define N_DIM 4096
#define E_DIM 2048
#define P_DIM 32
#define NS1 32   // n-splits for proto1
#define FS2 8    // f-splits for proto2

typedef __attribute__((ext_vector_type(8))) short short8;
typedef __attribute__((ext_vector_type(4))) float f32x4;

__device__ __forceinline__ unsigned short f2bf(float f) {
  unsigned u = __float_as_uint(f);
  return (unsigned short)((u + 0x7FFFu + ((u >> 16) & 1u)) >> 16);
}

// ---------------------------------------------------------------------------
// A: K[b][n][p] = BN(proj_w @ vf), Ksq[b][n] = sum_p K^2.  grid 128, block 256
// ---------------------------------------------------------------------------
__global__ __launch_bounds__(256) void k_proj(
    const float* __restrict__ vf, const float* __restrict__ pw,
    const float* __restrict__ gamma, const float* __restrict__ beta,
    const float* __restrict__ mean, const float* __restrict__ var,
    float* __restrict__ Kf, float* __restrict__ Ksq) {
  __shared__ float w_s[P_DIM * C_DIM];
  __shared__ float part_s[4][64][P_DIM + 1];
  __shared__ float kt_s[64][P_DIM + 1];
  __shared__ float sc_s[P_DIM], sb_s[P_DIM], sm_s[P_DIM];

  const int tid = threadIdx.x;
  const int b = blockIdx.x >> 6;
  const int n0 = (blockIdx.x & 63) << 6;

  for (int i = tid; i < P_DIM * C_DIM; i += 256) w_s[i] = pw[i];
  if (tid < P_DIM) {
    sc_s[tid] = gamma[tid] / sqrtf(var[tid] + 1e-5f);
    sb_s[tid] = beta[tid];
    sm_s[tid] = mean[tid];
  }
  __syncthreads();

  const int nl = tid & 63, cs = tid >> 6;
  const float* vbase = vf + (size_t)b * C_DIM * N_DIM + n0 + nl;
  float acc[P_DIM];
#pragma unroll
  for (int p = 0; p < P_DIM; ++p) acc[p] = 0.f;
#pragma unroll 4
  for (int cc = 0; cc < 64; ++cc) {
    int c = cs * 64 + cc;
    float v = vbase[(size_t)c * N_DIM];
    const float* wc = &w_s[c];
#pragma unroll
    for (int p = 0; p < P_DIM; ++p) acc[p] = fmaf(wc[p * C_DIM], v, acc[p]);
  }
#pragma unroll
  for (int p = 0; p < P_DIM; ++p) part_s[cs][nl][p] = acc[p];
  __syncthreads();

  for (int i = tid; i < 64 * P_DIM; i += 256) {
    int n_l = i >> 5, p = i & 31;
    float s = ((part_s[0][n_l][p] + part_s[1][n_l][p]) + part_s[2][n_l][p]) +
              part_s[3][n_l][p];
    float k = (s - sm_s[p]) * sc_s[p] + sb_s[p];
    Kf[((size_t)(b * N_DIM + n0 + n_l)) * P_DIM + p] = k;
    kt_s[n_l][p] = k;
  }
  __syncthreads();
  if (tid < 64) {
    float q = 0.f;
#pragma unroll
    for (int p = 0; p < P_DIM; ++p) q = fmaf(kt_s[tid][p], kt_s[tid][p], q);
    Ksq[b * N_DIM + n0 + tid] = q;
  }
}

// ---------------------------------------------------------------------------
// A2: VT[b][n][c] = vf[b][c][n].  grid 512, block 256
// ---------------------------------------------------------------------------
__global__ __launch_bounds__(256) void k_transpose(const float* __restrict__ vf,
                                                   float* __restrict__ VT) {
  __shared__ float t_s[64][65];
  const int tid = threadIdx.x;
  const int b = blockIdx.x >> 8;
  const int n0 = ((blockIdx.x >> 2) & 63) << 6;
  const int c0 = (blockIdx.x & 3) << 6;
  const float* src = vf + (size_t)b * C_DIM * N_DIM;
#pragma unroll
  for (int i = 0; i < 16; ++i) {
    int idx = tid + i * 256;
    int n_l = idx & 63, c_l = idx >> 6;
    t_s[c_l][n_l] = src[(size_t)(c0 + c_l) * N_DIM + n0 + n_l];
  }
  __syncthreads();
  float* dst = VT + (size_t)b * N_DIM * C_DIM;
#pragma unroll
  for (int i = 0; i < 16; ++i) {
    int idx = tid + i * 256;
    int c_l = idx & 63, n_l = idx >> 6;
    dst[(size_t)(n0 + n_l) * C_DIM + c0 + c_l] = t_s[c_l][n_l];
  }
}

// ---------------------------------------------------------------------------
// B1: P1part[ns][b][e][p] = sum_{n in 128-chunk} inc[b][n][e]*K[b][n][p]
// grid 256 (= bs * 4 etiles(512e) * 32 nsplits), block 256, 2 e per thread.
// ---------------------------------------------------------------------------
__global__ __launch_bounds__(256) void k_proto1(const float* __restrict__ inc,
                                                const float* __restrict__ Kf,
                                                float* __restrict__ part) {
  __shared__ float k_s[64][P_DIM];
  const int tid = threadIdx.x;
  const int b = blockIdx.x >> 7;
  const int et = (blockIdx.x >> 5) & 3;
  const int ns = blockIdx.x & 31;
  const int e0 = et << 9;
  const int nbase = ns << 7;

  float acc0[P_DIM], acc1[P_DIM];
#pragma unroll
  for (int p = 0; p < P_DIM; ++p) { acc0[p] = 0.f; acc1[p] = 0.f; }

  for (int nt = 0; nt < 2; ++nt) {
    int n0 = nbase + nt * 64;
#pragma unroll
    for (int i = 0; i < 8; ++i) {
      int idx = tid + i * 256;
      ((float*)k_s)[idx] = Kf[((size_t)(b * N_DIM + n0)) * P_DIM + idx];
    }
    __syncthreads();
#pragma unroll 8
    for (int nn = 0; nn < 64; ++nn) {
      const float* irow = inc + ((size_t)(b * N_DIM + n0 + nn)) * E_DIM + e0;
      float va = irow[tid];
      float vb = irow[tid + 256];
      const float4* kv4 = (const float4*)k_s[nn];
#pragma unroll
      for (int q = 0; q < 8; ++q) {
        float4 kv = kv4[q];
        acc0[4 * q + 0] = fmaf(va, kv.x, acc0[4 * q + 0]);
        acc0[4 * q + 1] = fmaf(va, kv.y, acc0[4 * q + 1]);
        acc0[4 * q + 2] = fmaf(va, kv.z, acc0[4 * q + 2]);
        acc0[4 * q + 3] = fmaf(va, kv.w, acc0[4 * q + 3]);
        acc1[4 * q + 0] = fmaf(vb, kv.x, acc1[4 * q + 0]);
        acc1[4 * q + 1] = fmaf(vb, kv.y, acc1[4 * q + 1]);
        acc1[4 * q + 2] = fmaf(vb, kv.z, acc1[4 * q + 2]);
        acc1[4 * q + 3] = fmaf(vb, kv.w, acc1[4 * q + 3]);
      }
    }
    __syncthreads();
  }
  float* dst0 = part + (size_t)ns * (BS * E_DIM * P_DIM) +
                ((size_t)(b * E_DIM + e0 + tid)) * P_DIM;
  float* dst1 = dst0 + 256 * P_DIM;
#pragma unroll
  for (int q = 0; q < 8; ++q) {
    ((float4*)dst0)[q] = make_float4(acc0[4 * q + 0], acc0[4 * q + 1],
                                     acc0[4 * q + 2], acc0[4 * q + 3]);
    ((float4*)dst1)[q] = make_float4(acc1[4 * q + 0], acc1[4 * q + 1],
                                     acc1[4 * q + 2], acc1[4 * q + 3]);
  }
}

// ---------------------------------------------------------------------------
// B2: proto1 = sum of 32 partials.  grid 512, block 256
// ---------------------------------------------------------------------------
__global__ __launch_bounds__(256) void k_red32(const float* __restrict__ part,
                                               float* __restrict__ outp) {
  int g = blockIdx.x * 256 + threadIdx.x;
  float v = 0.f;
#pragma unroll
  for (int s = 0; s < NS1; ++s)
    v += part[(size_t)s * (BS * E_DIM * P_DIM) + g];
  outp[g] = v;
}

// ---------------------------------------------------------------------------
// B3: P2part[fs][b][e][p] = sum_{f in 256-chunk} ied[b][e][f]*proto1[b][f][p]
// grid 256, block 256, [2e][8p]/thread. ALSO emits ied_h = bf16(ied).
// ---------------------------------------------------------------------------
__global__ __launch_bounds__(256) void k_proto2(const float* __restrict__ ied,
                                                const float* __restrict__ proto1,
                                                float* __restrict__ part,
                                                short* __restrict__ ied_h) {
  __shared__ float inv_s[128][33];
  __shared__ float p1_s[32][P_DIM];
  const int tid = threadIdx.x;
  const int b = blockIdx.x >> 7;
  const int et = (blockIdx.x >> 3) & 15;
  const int fs = blockIdx.x & 7;
  const int e0 = et << 7;
  const int fbase = fs << 8;
  const int e_l = tid & 63, pg = tid >> 6;

  float acc0[8], acc1[8];
#pragma unroll
  for (int q = 0; q < 8; ++q) { acc0[q] = 0.f; acc1[q] = 0.f; }

  for (int ft = 0; ft < 8; ++ft) {
    int f0 = fbase + ft * 32;
    __syncthreads();
#pragma unroll
    for (int i = 0; i < 16; ++i) {
      int idx = tid + i * 256;
      int e_r = idx >> 5, f_l = idx & 31;
      size_t gidx = ((size_t)(b * E_DIM + e0 + e_r)) * E_DIM + f0 + f_l;
      float v = ied[gidx];
      inv_s[e_r][f_l] = v;
      ied_h[gidx] = (short)f2bf(v);
    }
#pragma unroll
    for (int i = 0; i < 4; ++i) {
      int idx = tid + i * 256;
      ((float*)p1_s)[idx] = proto1[((size_t)(b * E_DIM + f0)) * P_DIM + idx];
    }
    __syncthreads();
#pragma unroll
    for (int ff = 0; ff < 32; ++ff) {
      float a0 = inv_s[e_l][ff];
      float a1 = inv_s[e_l + 64][ff];
      const float4* pv4 = (const float4*)&p1_s[ff][pg * 8];
      float4 pv0 = pv4[0], pv1 = pv4[1];
      acc0[0] = fmaf(a0, pv0.x, acc0[0]);
      acc0[1] = fmaf(a0, pv0.y, acc0[1]);
      acc0[2] = fmaf(a0, pv0.z, acc0[2]);
      acc0[3] = fmaf(a0, pv0.w, acc0[3]);
      acc0[4] = fmaf(a0, pv1.x, acc0[4]);
      acc0[5] = fmaf(a0, pv1.y, acc0[5]);
      acc0[6] = fmaf(a0, pv1.z, acc0[6]);
      acc0[7] = fmaf(a0, pv1.w, acc0[7]);
      acc1[0] = fmaf(a1, pv0.x, acc1[0]);
      acc1[1] = fmaf(a1, pv0.y, acc1[1]);
      acc1[2] = fmaf(a1, pv0.z, acc1[2]);
      acc1[3] = fmaf(a1, pv0.w, acc1[3]);
      acc1[4] = fmaf(a1, pv1.x, acc1[4]);
      acc1[5] = fmaf(a1, pv1.y, acc1[5]);
      acc1[6] = fmaf(a1, pv1.z, acc1[6]);
      acc1[7] = fmaf(a1, pv1.w, acc1[7]);
    }
  }
  float* dst0 = part + (size_t)fs * (BS * E_DIM * P_DIM) +
                ((size_t)(b * E_DIM + e0 + e_l)) * P_DIM + pg * 8;
  float* dst1 = dst0 + 64 * P_DIM;
  ((float4*)dst0)[0] = make_float4(acc0[0], acc0[1], acc0[2], acc0[3]);
  ((float4*)dst0)[1] = make_float4(acc0[4], acc0[5], acc0[6], acc0[7]);
  ((float4*)dst1)[0] = make_float4(acc1[0], acc1[1], acc1[2], acc1[3]);
  ((float4*)dst1)[1] = make_float4(acc1[4], acc1[5], acc1[6], acc1[7]);
}

// ---------------------------------------------------------------------------
// B4: proto = sum of 8 partials; proto_sq = rownorm^2.  grid 512, block 256
// ---------------------------------------------------------------------------
__global__ __launch_bounds__(256) void k_red8sq(const float* __restrict__ part,
                                                float* __restrict__ proto,
                                                float* __restrict__ psq) {
  int g = blockIdx.x * 256 + threadIdx.x;
  float v = 0.f;
#pragma unroll
  for (int s = 0; s < FS2; ++s)
    v += part[(size_t)s * (BS * E_DIM * P_DIM) + g];
  proto[g] = v;
  float q = v * v;
#pragma unroll
  for (int m = 1; m <= 16; m <<= 1) q += __shfl_xor(q, m, 64);
  if ((threadIdx.x & 31) == 0) psq[g >> 5] = q;
}

// ---------------------------------------------------------------------------
// C1: per-(edge, 128-n-chunk) max of g = 2*<proto_e,K_n> - Ksq_n
// grid 2048 (= bs * 32 etiles(64e) * 32 chunks), block 256.
// R3-proven inner structure VERBATIM (4x4 microtile, acc[4][4], no spill);
// only the decomposition changed: one 128-n chunk per block (t = 0..1).
// Per-(e,n) fmaf chain identical -> chunkg bitwise identical.
// ---------------------------------------------------------------------------
__global__ __launch_bounds__(256) void k_gmax(const float* __restrict__ Kf,
                                              const float* __restrict__ Ksq,
                                              const float* __restrict__ proto,
                                              float* __restrict__ chunkg) {
  __shared__ float a_s[P_DIM][64];
  __shared__ float b_s[P_DIM][64];
  __shared__ float q_s[64];
  const int tid = threadIdx.x;
  const int b = blockIdx.x >> 10;
  const int et = (blockIdx.x >> 5) & 31;
  const int ch = blockIdx.x & 31;
  const int e0 = et << 6;
  const int n0b = ch << 7;

  {
    int p = tid >> 6, e = tid & 63;
#pragma unroll
    for (int r = 0; r < 8; ++r)
      a_s[p + r * 4][e] =
          proto[((size_t)(b * E_DIM + e0 + e)) * P_DIM + p + r * 4];
  }
  const int te = tid >> 4, tn = tid & 15;
  float gm[4];
#pragma unroll
  for (int i = 0; i < 4; ++i) gm[i] = -INFINITY;

  for (int t = 0; t < 2; ++t) {
    const int n0 = n0b + t * 64;
    __syncthreads();
    {
      int p = tid >> 6, n = tid & 63;
#pragma unroll
      for (int r = 0; r < 8; ++r)
        b_s[p + r * 4][n] =
            Kf[((size_t)(b * N_DIM + n0 + n)) * P_DIM + p + r * 4];
      if (tid < 64) q_s[tid] = Ksq[b * N_DIM + n0 + tid];
    }
    __syncthreads();

    float acc[4][4];
#pragma unroll
    for (int i = 0; i < 4; ++i)
#pragma unroll
      for (int j = 0; j < 4; ++j) acc[i][j] = 0.f;

#pragma unroll
    for (int p = 0; p < P_DIM; ++p) {
      float4 av = *(const float4*)&a_s[p][te << 2];
      float4 bv = *(const float4*)&b_s[p][tn << 2];
      acc[0][0] = fmaf(av.x, bv.x, acc[0][0]);
      acc[0][1] = fmaf(av.x, bv.y, acc[0][1]);
      acc[0][2] = fmaf(av.x, bv.z, acc[0][2]);
      acc[0][3] = fmaf(av.x, bv.w, acc[0][3]);
      acc[1][0] = fmaf(av.y, bv.x, acc[1][0]);
      acc[1][1] = fmaf(av.y, bv.y, acc[1][1]);
      acc[1][2] = fmaf(av.y, bv.z, acc[1][2]);
      acc[1][3] = fmaf(av.y, bv.w, acc[1][3]);
      acc[2][0] = fmaf(av.z, bv.x, acc[2][0]);
      acc[2][1] = fmaf(av.z, bv.y, acc[2][1]);
      acc[2][2] = fmaf(av.z, bv.z, acc[2][2]);
      acc[2][3] = fmaf(av.z, bv.w, acc[2][3]);
      acc[3][0] = fmaf(av.w, bv.x, acc[3][0]);
      acc[3][1] = fmaf(av.w, bv.y, acc[3][1]);
      acc[3][2] = fmaf(av.w, bv.z, acc[3][2]);
      acc[3][3] = fmaf(av.w, bv.w, acc[3][3]);
    }
#pragma unroll
    for (int i = 0; i < 4; ++i)
#pragma unroll
      for (int j = 0; j < 4; ++j) {
        float g = fmaf(2.0f, acc[i][j], -q_s[(tn << 2) + j]);
        gm[i] = fmaxf(gm[i], g);
      }

    if (t & 1) {
#pragma unroll
      for (int i = 0; i < 4; ++i) {
        float v = gm[i];
        v = fmaxf(v, __shfl_xor(v, 1, 64));
        v = fmaxf(v, __shfl_xor(v, 2, 64));
        v = fmaxf(v, __shfl_xor(v, 4, 64));
        v = fmaxf(v, __shfl_xor(v, 8, 64));
        if (tn == 0)
          chunkg[((size_t)(b * E_DIM + e0 + (te << 2) + i)) * 32 + ch] = v;
        gm[i] = -INFINITY;
      }
    }
  }
}

// ---------------------------------------------------------------------------
// C2: per-edge sparse softmax-aggregate. One wave per edge.
// grid 1024, block 256 (4 waves).
// ---------------------------------------------------------------------------
__device__ __forceinline__ float edge_logit(const float* __restrict__ Kb,
                                            const float* __restrict__ Qb,
                                            const float* pr, float psqv,
                                            int n) {
  const float4* kp = (const float4*)(Kb + (size_t)n * P_DIM);
  float i0 = 0.f, i1 = 0.f, i2 = 0.f, i3 = 0.f;
#pragma unroll
  for (int q = 0; q < 8; ++q) {
    float4 kv = kp[q];
    i0 = fmaf(pr[4 * q + 0], kv.x, i0);
    i1 = fmaf(pr[4 * q + 1], kv.y, i1);
    i2 = fmaf(pr[4 * q + 2], kv.z, i2);
    i3 = fmaf(pr[4 * q + 3], kv.w, i3);
  }
  float inner = (i0 + i1) + (i2 + i3);
  float cost = fmaf(-2.0f, inner, psqv + Qb[n]);
  const float tau_eps = 0.1f + 1e-8f;
  return (-cost) / tau_eps;
}

__global__ __launch_bounds__(256) void k_sparse(
    const float* __restrict__ Kf, const float* __restrict__ Ksq,
    const float* __restrict__ proto, const float* __restrict__ psq,
    const float* __restrict__ VT, const float* __restrict__ chunkg,
    float* __restrict__ EF0) {
  const int tid = threadIdx.x;
  const int lane = tid & 63;
  const int eg = blockIdx.x * 4 + (tid >> 6);
  const int b = eg >> 11;
  const float* Kb = Kf + (size_t)b * N_DIM * P_DIM;
  const float* Qb = Ksq + (size_t)b * N_DIM;

  float cg = (lane < 32) ? chunkg[(size_t)eg * 32 + lane] : -INFINITY;
  float gmax = cg;
#pragma unroll
  for (int m = 1; m <= 32; m <<= 1) gmax = fmaxf(gmax, __shfl_xor(gmax, m, 64));
  unsigned long long live = __ballot(cg > gmax - 20.0f);

  float pr[P_DIM];
  const float* pe = proto + (size_t)eg * P_DIM;
#pragma unroll
  for (int p = 0; p < P_DIM; ++p) pr[p] = pe[p];
  const float psqv = psq[eg];

  float L = -INFINITY;
  unsigned long long m0 = live;
  while (m0) {
    int c = __ffsll(m0) - 1;
    m0 &= m0 - 1;
    int n = (c << 7) + lane;
    L = fmaxf(L, edge_logit(Kb, Qb, pr, psqv, n));
    L = fmaxf(L, edge_logit(Kb, Qb, pr, psqv, n + 64));
  }
#pragma unroll
  for (int m = 1; m <= 32; m <<= 1) L = fmaxf(L, __shfl_xor(L, m, 64));

  float4 acc = make_float4(0.f, 0.f, 0.f, 0.f);
  float sw = 0.f;
  const float* Vb = VT + (size_t)b * N_DIM * C_DIM;
  m0 = live;
  while (m0) {
    int c = __ffsll(m0) - 1;
    m0 &= m0 - 1;
#pragma unroll
    for (int h = 0; h < 2; ++h) {
      int n = (c << 7) + (h << 6) + lane;
      float l = edge_logit(Kb, Qb, pr, psqv, n);
      float d = l - L;
      float wgt = (d > -25.0f) ? expf(d) : 0.f;
      sw += wgt;
      unsigned long long hits = __ballot(wgt > 0.f);
      while (hits) {
        int src = __ffsll(hits) - 1;
        hits &= hits - 1;
        float wv = __shfl(wgt, src, 64);
        int nv = (c << 7) + (h << 6) + src;
        const float4 vrow =
            *(const float4*)(Vb + (size_t)nv * C_DIM + (lane << 2));
        acc.x = fmaf(wv, vrow.x, acc.x);
        acc.y = fmaf(wv, vrow.y, acc.y);
        acc.z = fmaf(wv, vrow.z, acc.z);
        acc.w = fmaf(wv, vrow.w, acc.w);
      }
    }
  }
#pragma unroll
  for (int m = 1; m <= 32; m <<= 1) sw += __shfl_xor(sw, m, 64);

  float* dst = EF0 + (size_t)eg * C_DIM + (lane << 2);
  *(float4*)dst =
      make_float4(acc.x / sw, acc.y / sw, acc.z / sw, acc.w / sw);
}

// ---------------------------------------------------------------------------
// C3: EF0t[b][c][f] = bf16(EF0[b][f][c]).  grid 256, block 256, 64x64 tiles
// ---------------------------------------------------------------------------
__global__ __launch_bounds__(256) void k_ef0t(const float* __restrict__ EF0,
                                              short* __restrict__ EF0t) {
  __shared__ short sh[64][72];
  const int tid = threadIdx.x;
  const int b = blockIdx.x >> 7;
  const int ft = (blockIdx.x >> 2) & 31;
  const int ct = blockIdx.x & 3;
  const int f0 = ft << 6, c0 = ct << 6;
#pragma unroll
  for (int i = 0; i < 4; ++i) {
    int idx = tid + i * 256;
    int f_l = idx >> 4, cc = idx & 15;
    float4 v =
        *(const float4*)&EF0[((size_t)(b * E_DIM + f0 + f_l)) * C_DIM + c0 +
                             cc * 4];
    sh[cc * 4 + 0][f_l] = (short)f2bf(v.x);
    sh[cc * 4 + 1][f_l] = (short)f2bf(v.y);
    sh[cc * 4 + 2][f_l] = (short)f2bf(v.z);
    sh[cc * 4 + 3][f_l] = (short)f2bf(v.w);
  }
  __syncthreads();
#pragma unroll
  for (int i = 0; i < 2; ++i) {
    int idx = tid + i * 256;
    int c_l = idx >> 3, ch = idx & 7;
    short8 v = *(const short8*)&sh[c_l][ch * 8];
    *(short8*)&EF0t[((size_t)(b * C_DIM + c0 + c_l)) * E_DIM + f0 + ch * 8] = v;
  }
}

// ---------------------------------------------------------------------------
// D: bf16 MFMA GEMM, full K (no split), double-buffered LDS + reg prefetch.
// out[b][c][e] = sum_f ied[b][e][f] * EF0[b][f][c].
// grid 256 (= 2b * 32et * 4ct), block 256 (4 waves). Tile 64e x 64c, BK=64,
// wave quad 32x32. LDS XOR-swizzle (byte ^= (row&7)<<4), 1 barrier/K-step.
// ---------------------------------------------------------------------------
__device__ __forceinline__ short8 lds_frag(const short* s, int row, int k) {
  int off = (((row << 6) + k) << 1) ^ ((row & 7) << 4);
  return *(const short8*)((const char*)s + off);
}
__device__ __forceinline__ void lds_put(short* s, int row, int k, short8 v) {
  int off = (((row << 6) + k) << 1) ^ ((row & 7) << 4);
  *(short8*)((char*)s + off) = v;
}

__global__ __launch_bounds__(256) void k_final_mfma(
    const short* __restrict__ Ah, const short* __restrict__ Bh,
    float* __restrict__ out) {
  __shared__ short As[2][64 * 64];
  __shared__ short Bs[2][64 * 64];
  __shared__ float Cs[64][68];

  const int tid = threadIdx.x;
  const int lane = tid & 63;
  const int w = tid >> 6;
  const int ct = blockIdx.x & 3;
  const int et = (blockIdx.x >> 2) & 31;
  const int b = blockIdx.x >> 7;
  const int e0 = et << 6, c0 = ct << 6;

  const int we = (w >> 1) << 5;   // wave e-quadrant offset
  const int wc = (w & 1) << 5;    // wave c-quadrant offset
  const int row = tid >> 2, ch = tid & 3;

  const short* gA = Ah + ((size_t)(b * E_DIM + e0 + row)) * E_DIM;
  const short* gB = Bh + ((size_t)(b * C_DIM + c0 + row)) * E_DIM;

  f32x4 z = {0.f, 0.f, 0.f, 0.f};
  f32x4 acc00 = z, acc01 = z, acc10 = z, acc11 = z;

  // prologue: tile 0 -> LDS[0]
  {
    const short8* pa = (const short8*)(gA + ch * 16);
    const short8* pb = (const short8*)(gB + ch * 16);
    short8 a0 = pa[0], a1 = pa[1];
    short8 b0 = pb[0], b1 = pb[1];
    lds_put(As[0], row, ch * 16, a0);
    lds_put(As[0], row, ch * 16 + 8, a1);
    lds_put(Bs[0], row, ch * 16, b0);
    lds_put(Bs[0], row, ch * 16 + 8, b1);
  }
  __syncthreads();

  for (int kt = 0; kt < 32; ++kt) {
    const int cur = kt & 1;
    short8 na0, na1, nb0, nb1;
    if (kt < 31) {  // issue next-tile loads early (hide HBM under MFMA)
      const int f1 = (kt + 1) << 6;
      const short8* pa = (const short8*)(gA + f1 + ch * 16);
      const short8* pb = (const short8*)(gB + f1 + ch * 16);
      na0 = pa[0]; na1 = pa[1]; nb0 = pb[0]; nb1 = pb[1];
    }
#pragma unroll
    for (int s = 0; s < 2; ++s) {
      const int kb = (s << 5) + ((lane >> 4) << 3);
      short8 fa0 = lds_frag(As[cur], we + (lane & 15), kb);
      short8 fa1 = lds_frag(As[cur], we + 16 + (lane & 15), kb);
      short8 fb0 = lds_frag(Bs[cur], wc + (lane & 15), kb);
      short8 fb1 = lds_frag(Bs[cur], wc + 16 + (lane & 15), kb);
      acc00 = __builtin_amdgcn_mfma_f32_16x16x32_bf16(fa0, fb0, acc00, 0, 0, 0);
      acc01 = __builtin_amdgcn_mfma_f32_16x16x32_bf16(fa0, fb1, acc01, 0, 0, 0);
      acc10 = __builtin_amdgcn_mfma_f32_16x16x32_bf16(fa1, fb0, acc10, 0, 0, 0);
      acc11 = __builtin_amdgcn_mfma_f32_16x16x32_bf16(fa1, fb1, acc11, 0, 0, 0);
    }
    if (kt < 31) {  // write into the buffer last read at kt-1 (barrier-safe)
      lds_put(As[cur ^ 1], row, ch * 16, na0);
      lds_put(As[cur ^ 1], row, ch * 16 + 8, na1);
      lds_put(Bs[cur ^ 1], row, ch * 16, nb0);
      lds_put(Bs[cur ^ 1], row, ch * 16 + 8, nb1);
    }
    __syncthreads();
  }

  // epilogue: stage transposed [c][e] in LDS, then coalesced fp32 writes
  const int fr = lane & 15, fq = lane >> 4;
#pragma unroll
  for (int r = 0; r < 4; ++r) {
    Cs[wc + fr][we + fq * 4 + r] = acc00[r];
    Cs[wc + 16 + fr][we + fq * 4 + r] = acc01[r];
    Cs[wc + fr][we + 16 + fq * 4 + r] = acc10[r];
    Cs[wc + 16 + fr][we + 16 + fq * 4 + r] = acc11[r];
  }
  __syncthreads();
  {
    const int c_l = tid >> 2, cch = tid & 3;
    float* dst = out + ((size_t)(b * C_DIM + c0 + c_l)) * E_DIM + e0;
#pragma unroll
    for (int r = 0; r < 4; ++r) {
      float4 v = *(const float4*)&Cs[c_l][cch * 16 + r * 4];
      *(float4*)&dst[cch * 16 + r * 4] = v;
    }
  }
}

// ---------------------------------------------------------------------------
extern "C" void kernel_launch(void* const* d_in, const int* in_sizes, int n_in,
                              void* d_out, int out_size, void* d_ws,
                              size_t ws_size, hipStream_t stream) {
  (void)in_sizes; (void)n_in; (void)out_size; (void)ws_size;
  const float* vf  = (const float*)d_in[0];
  const float* inc = (const float*)d_in[1];
  const float* ied = (const float*)d_in[2];
  const float* pw  = (const float*)d_in[5];
  const float* gm  = (const float*)d_in[6];
  const float* bt  = (const float*)d_in[7];
  const float* mn  = (const float*)d_in[8];
  const float* vr  = (const float*)d_in[9];
  float* out = (float*)d_out;

  float* ws = (float*)d_ws;
  float* VT      = ws;                  // 2,097,152 f
  float* Kf      = VT + 2097152;        //   262,144
  float* Ksq     = Kf + 262144;         //     8,192
  float* proto1  = Ksq + 8192;          //   131,072
  float* proto   = proto1 + 131072;     //   131,072
  float* psq     = proto + 131072;      //     4,096
  float* P1p     = psq + 4096;          // 32*131,072 = 4,194,304
  float* P2p     = P1p + 4194304;       //  8*131,072 = 1,048,576
  float* EF0     = P2p + 1048576;       // 1,048,576
  float* chunkg  = EF0 + 1048576;       //   131,072
  short* ied_h   = (short*)(chunkg + 131072);            // 8,388,608 shorts
  short* EF0t    = (short*)(chunkg + 131072 + 4194304);  // 1,048,576 shorts
  // total ~47 MB

  k_proj<<<dim3(128), dim3(256), 0, stream>>>(vf, pw, gm, bt, mn, vr, Kf, Ksq);
  k_transpose<<<dim3(512), dim3(256), 0, stream>>>(vf, VT);
  k_proto1<<<dim3(256), dim3(256), 0, stream>>>(inc, Kf, P1p);
  k_red32<<<dim3(512), dim3(256), 0, stream>>>(P1p, proto1);
  k_proto2<<<dim3(256), dim3(256), 0, stream>>>(ied, proto1, P2p, ied_h);
  k_red8sq<<<dim3(512), dim3(256), 0, stream>>>(P2p, proto, psq);
  k_gmax<<<dim3(2048), dim3(256), 0, stream>>>(Kf, Ksq, proto, chunkg);
  k_sparse<<<dim3(1024), dim3(256), 0, stream>>>(Kf, Ksq, proto, psq, VT,
                                                 chunkg, EF0);
  k_ef0t<<<dim3(256), dim3(256), 0, stream>>>(EF0, EF0t);
  k_final_mfma<<<dim3(256), dim3(256), 0, stream>>>(ied_h, EF0t, out);
}

// Round 11
// 158.516 us; speedup vs baseline: 1.2988x; 1.2177x over previous
//
#include <hip/hip_runtime.h>
#include <math.h>

#define BS 2
#define C_DIM 256
#define N_DIM 4096
#define E_DIM 2048
#define P_DIM 32
#define NS1 32   // n-splits for proto1
#define FS2 8    // f-splits for proto2

typedef __attribute__((ext_vector_type(8))) short short8;
typedef __attribute__((ext_vector_type(4))) float f32x4;

__device__ __forceinline__ unsigned short f2bf(float f) {
  unsigned u = __float_as_uint(f);
  return (unsigned short)((u + 0x7FFFu + ((u >> 16) & 1u)) >> 16);
}

// ---------------------------------------------------------------------------
// A: K[b][n][p] = BN(proj_w @ vf), Ksq[b][n] = sum_p K^2.  grid 128, block 256
// ---------------------------------------------------------------------------
__global__ __launch_bounds__(256) void k_proj(
    const float* __restrict__ vf, const float* __restrict__ pw,
    const float* __restrict__ gamma, const float* __restrict__ beta,
    const float* __restrict__ mean, const float* __restrict__ var,
    float* __restrict__ Kf, float* __restrict__ Ksq) {
  __shared__ float w_s[P_DIM * C_DIM];
  __shared__ float part_s[4][64][P_DIM + 1];
  __shared__ float kt_s[64][P_DIM + 1];
  __shared__ float sc_s[P_DIM], sb_s[P_DIM], sm_s[P_DIM];

  const int tid = threadIdx.x;
  const int b = blockIdx.x >> 6;
  const int n0 = (blockIdx.x & 63) << 6;

  for (int i = tid; i < P_DIM * C_DIM; i += 256) w_s[i] = pw[i];
  if (tid < P_DIM) {
    sc_s[tid] = gamma[tid] / sqrtf(var[tid] + 1e-5f);
    sb_s[tid] = beta[tid];
    sm_s[tid] = mean[tid];
  }
  __syncthreads();

  const int nl = tid & 63, cs = tid >> 6;
  const float* vbase = vf + (size_t)b * C_DIM * N_DIM + n0 + nl;
  float acc[P_DIM];
#pragma unroll
  for (int p = 0; p < P_DIM; ++p) acc[p] = 0.f;
#pragma unroll 4
  for (int cc = 0; cc < 64; ++cc) {
    int c = cs * 64 + cc;
    float v = vbase[(size_t)c * N_DIM];
    const float* wc = &w_s[c];
#pragma unroll
    for (int p = 0; p < P_DIM; ++p) acc[p] = fmaf(wc[p * C_DIM], v, acc[p]);
  }
#pragma unroll
  for (int p = 0; p < P_DIM; ++p) part_s[cs][nl][p] = acc[p];
  __syncthreads();

  for (int i = tid; i < 64 * P_DIM; i += 256) {
    int n_l = i >> 5, p = i & 31;
    float s = ((part_s[0][n_l][p] + part_s[1][n_l][p]) + part_s[2][n_l][p]) +
              part_s[3][n_l][p];
    float k = (s - sm_s[p]) * sc_s[p] + sb_s[p];
    Kf[((size_t)(b * N_DIM + n0 + n_l)) * P_DIM + p] = k;
    kt_s[n_l][p] = k;
  }
  __syncthreads();
  if (tid < 64) {
    float q = 0.f;
#pragma unroll
    for (int p = 0; p < P_DIM; ++p) q = fmaf(kt_s[tid][p], kt_s[tid][p], q);
    Ksq[b * N_DIM + n0 + tid] = q;
  }
}

// ---------------------------------------------------------------------------
// A2: VT[b][n][c] = vf[b][c][n].  grid 512, block 256
// ---------------------------------------------------------------------------
__global__ __launch_bounds__(256) void k_transpose(const float* __restrict__ vf,
                                                   float* __restrict__ VT) {
  __shared__ float t_s[64][65];
  const int tid = threadIdx.x;
  const int b = blockIdx.x >> 8;
  const int n0 = ((blockIdx.x >> 2) & 63) << 6;
  const int c0 = (blockIdx.x & 3) << 6;
  const float* src = vf + (size_t)b * C_DIM * N_DIM;
#pragma unroll
  for (int i = 0; i < 16; ++i) {
    int idx = tid + i * 256;
    int n_l = idx & 63, c_l = idx >> 6;
    t_s[c_l][n_l] = src[(size_t)(c0 + c_l) * N_DIM + n0 + n_l];
  }
  __syncthreads();
  float* dst = VT + (size_t)b * N_DIM * C_DIM;
#pragma unroll
  for (int i = 0; i < 16; ++i) {
    int idx = tid + i * 256;
    int c_l = idx & 63, n_l = idx >> 6;
    dst[(size_t)(n0 + n_l) * C_DIM + c0 + c_l] = t_s[c_l][n_l];
  }
}

// ---------------------------------------------------------------------------
// B1: P1part[ns][b][e][p] = sum_{n in 128-chunk} inc[b][n][e]*K[b][n][p]
// grid 256 (= bs * 4 etiles(512e) * 32 nsplits), block 256, 2 e per thread.
// ---------------------------------------------------------------------------
__global__ __launch_bounds__(256) void k_proto1(const float* __restrict__ inc,
                                                const float* __restrict__ Kf,
                                                float* __restrict__ part) {
  __shared__ float k_s[64][P_DIM];
  const int tid = threadIdx.x;
  const int b = blockIdx.x >> 7;
  const int et = (blockIdx.x >> 5) & 3;
  const int ns = blockIdx.x & 31;
  const int e0 = et << 9;
  const int nbase = ns << 7;

  float acc0[P_DIM], acc1[P_DIM];
#pragma unroll
  for (int p = 0; p < P_DIM; ++p) { acc0[p] = 0.f; acc1[p] = 0.f; }

  for (int nt = 0; nt < 2; ++nt) {
    int n0 = nbase + nt * 64;
#pragma unroll
    for (int i = 0; i < 8; ++i) {
      int idx = tid + i * 256;
      ((float*)k_s)[idx] = Kf[((size_t)(b * N_DIM + n0)) * P_DIM + idx];
    }
    __syncthreads();
#pragma unroll 8
    for (int nn = 0; nn < 64; ++nn) {
      const float* irow = inc + ((size_t)(b * N_DIM + n0 + nn)) * E_DIM + e0;
      float va = irow[tid];
      float vb = irow[tid + 256];
      const float4* kv4 = (const float4*)k_s[nn];
#pragma unroll
      for (int q = 0; q < 8; ++q) {
        float4 kv = kv4[q];
        acc0[4 * q + 0] = fmaf(va, kv.x, acc0[4 * q + 0]);
        acc0[4 * q + 1] = fmaf(va, kv.y, acc0[4 * q + 1]);
        acc0[4 * q + 2] = fmaf(va, kv.z, acc0[4 * q + 2]);
        acc0[4 * q + 3] = fmaf(va, kv.w, acc0[4 * q + 3]);
        acc1[4 * q + 0] = fmaf(vb, kv.x, acc1[4 * q + 0]);
        acc1[4 * q + 1] = fmaf(vb, kv.y, acc1[4 * q + 1]);
        acc1[4 * q + 2] = fmaf(vb, kv.z, acc1[4 * q + 2]);
        acc1[4 * q + 3] = fmaf(vb, kv.w, acc1[4 * q + 3]);
      }
    }
    __syncthreads();
  }
  float* dst0 = part + (size_t)ns * (BS * E_DIM * P_DIM) +
                ((size_t)(b * E_DIM + e0 + tid)) * P_DIM;
  float* dst1 = dst0 + 256 * P_DIM;
#pragma unroll
  for (int q = 0; q < 8; ++q) {
    ((float4*)dst0)[q] = make_float4(acc0[4 * q + 0], acc0[4 * q + 1],
                                     acc0[4 * q + 2], acc0[4 * q + 3]);
    ((float4*)dst1)[q] = make_float4(acc1[4 * q + 0], acc1[4 * q + 1],
                                     acc1[4 * q + 2], acc1[4 * q + 3]);
  }
}

// ---------------------------------------------------------------------------
// B2: proto1 = sum of 32 partials.  grid 512, block 256
// ---------------------------------------------------------------------------
__global__ __launch_bounds__(256) void k_red32(const float* __restrict__ part,
                                               float* __restrict__ outp) {
  int g = blockIdx.x * 256 + threadIdx.x;
  float v = 0.f;
#pragma unroll
  for (int s = 0; s < NS1; ++s)
    v += part[(size_t)s * (BS * E_DIM * P_DIM) + g];
  outp[g] = v;
}

// ---------------------------------------------------------------------------
// B3: P2part[fs][b][e][p] = sum_{f in 256-chunk} ied[b][e][f]*proto1[b][f][p]
// grid 256, block 256, [2e][8p]/thread. ALSO emits ied_h = bf16(ied).
// ---------------------------------------------------------------------------
__global__ __launch_bounds__(256) void k_proto2(const float* __restrict__ ied,
                                                const float* __restrict__ proto1,
                                                float* __restrict__ part,
                                                short* __restrict__ ied_h) {
  __shared__ float inv_s[128][33];
  __shared__ float p1_s[32][P_DIM];
  const int tid = threadIdx.x;
  const int b = blockIdx.x >> 7;
  const int et = (blockIdx.x >> 3) & 15;
  const int fs = blockIdx.x & 7;
  const int e0 = et << 7;
  const int fbase = fs << 8;
  const int e_l = tid & 63, pg = tid >> 6;

  float acc0[8], acc1[8];
#pragma unroll
  for (int q = 0; q < 8; ++q) { acc0[q] = 0.f; acc1[q] = 0.f; }

  for (int ft = 0; ft < 8; ++ft) {
    int f0 = fbase + ft * 32;
    __syncthreads();
#pragma unroll
    for (int i = 0; i < 16; ++i) {
      int idx = tid + i * 256;
      int e_r = idx >> 5, f_l = idx & 31;
      size_t gidx = ((size_t)(b * E_DIM + e0 + e_r)) * E_DIM + f0 + f_l;
      float v = ied[gidx];
      inv_s[e_r][f_l] = v;
      ied_h[gidx] = (short)f2bf(v);
    }
#pragma unroll
    for (int i = 0; i < 4; ++i) {
      int idx = tid + i * 256;
      ((float*)p1_s)[idx] = proto1[((size_t)(b * E_DIM + f0)) * P_DIM + idx];
    }
    __syncthreads();
#pragma unroll
    for (int ff = 0; ff < 32; ++ff) {
      float a0 = inv_s[e_l][ff];
      float a1 = inv_s[e_l + 64][ff];
      const float4* pv4 = (const float4*)&p1_s[ff][pg * 8];
      float4 pv0 = pv4[0], pv1 = pv4[1];
      acc0[0] = fmaf(a0, pv0.x, acc0[0]);
      acc0[1] = fmaf(a0, pv0.y, acc0[1]);
      acc0[2] = fmaf(a0, pv0.z, acc0[2]);
      acc0[3] = fmaf(a0, pv0.w, acc0[3]);
      acc0[4] = fmaf(a0, pv1.x, acc0[4]);
      acc0[5] = fmaf(a0, pv1.y, acc0[5]);
      acc0[6] = fmaf(a0, pv1.z, acc0[6]);
      acc0[7] = fmaf(a0, pv1.w, acc0[7]);
      acc1[0] = fmaf(a1, pv0.x, acc1[0]);
      acc1[1] = fmaf(a1, pv0.y, acc1[1]);
      acc1[2] = fmaf(a1, pv0.z, acc1[2]);
      acc1[3] = fmaf(a1, pv0.w, acc1[3]);
      acc1[4] = fmaf(a1, pv1.x, acc1[4]);
      acc1[5] = fmaf(a1, pv1.y, acc1[5]);
      acc1[6] = fmaf(a1, pv1.z, acc1[6]);
      acc1[7] = fmaf(a1, pv1.w, acc1[7]);
    }
  }
  float* dst0 = part + (size_t)fs * (BS * E_DIM * P_DIM) +
                ((size_t)(b * E_DIM + e0 + e_l)) * P_DIM + pg * 8;
  float* dst1 = dst0 + 64 * P_DIM;
  ((float4*)dst0)[0] = make_float4(acc0[0], acc0[1], acc0[2], acc0[3]);
  ((float4*)dst0)[1] = make_float4(acc0[4], acc0[5], acc0[6], acc0[7]);
  ((float4*)dst1)[0] = make_float4(acc1[0], acc1[1], acc1[2], acc1[3]);
  ((float4*)dst1)[1] = make_float4(acc1[4], acc1[5], acc1[6], acc1[7]);
}

// ---------------------------------------------------------------------------
// B4: proto = sum of 8 partials; proto_sq = rownorm^2.  grid 512, block 256
// ---------------------------------------------------------------------------
__global__ __launch_bounds__(256) void k_red8sq(const float* __restrict__ part,
                                                float* __restrict__ proto,
                                                float* __restrict__ psq) {
  int g = blockIdx.x * 256 + threadIdx.x;
  float v = 0.f;
#pragma unroll
  for (int s = 0; s < FS2; ++s)
    v += part[(size_t)s * (BS * E_DIM * P_DIM) + g];
  proto[g] = v;
  float q = v * v;
#pragma unroll
  for (int m = 1; m <= 16; m <<= 1) q += __shfl_xor(q, m, 64);
  if ((threadIdx.x & 31) == 0) psq[g >> 5] = q;
}

// ---------------------------------------------------------------------------
// C1: per-(edge, 128-n-chunk) max of g = 2*<proto_e,K_n> - Ksq_n
// grid 512, block 256. 64e x 64n tiles, 4x4 microtile, p-major LDS.
// (R3/R8-proven version — empirical optimum; neighbors all regress.)
// ---------------------------------------------------------------------------
__global__ __launch_bounds__(256) void k_gmax(const float* __restrict__ Kf,
                                              const float* __restrict__ Ksq,
                                              const float* __restrict__ proto,
                                              float* __restrict__ chunkg) {
  __shared__ float a_s[P_DIM][64];
  __shared__ float b_s[P_DIM][64];
  __shared__ float q_s[64];
  const int tid = threadIdx.x;
  const int b = blockIdx.x >> 8;
  const int et = (blockIdx.x >> 3) & 31;
  const int ns = blockIdx.x & 7;
  const int e0 = et << 6;
  const int n0b = ns << 9;

  {
    int p = tid >> 6, e = tid & 63;
#pragma unroll
    for (int r = 0; r < 8; ++r)
      a_s[p + r * 4][e] =
          proto[((size_t)(b * E_DIM + e0 + e)) * P_DIM + p + r * 4];
  }
  const int te = tid >> 4, tn = tid & 15;
  float gm[4];
#pragma unroll
  for (int i = 0; i < 4; ++i) gm[i] = -INFINITY;

  for (int t = 0; t < 8; ++t) {
    const int n0 = n0b + t * 64;
    __syncthreads();
    {
      int p = tid >> 6, n = tid & 63;
#pragma unroll
      for (int r = 0; r < 8; ++r)
        b_s[p + r * 4][n] =
            Kf[((size_t)(b * N_DIM + n0 + n)) * P_DIM + p + r * 4];
      if (tid < 64) q_s[tid] = Ksq[b * N_DIM + n0 + tid];
    }
    __syncthreads();

    float acc[4][4];
#pragma unroll
    for (int i = 0; i < 4; ++i)
#pragma unroll
      for (int j = 0; j < 4; ++j) acc[i][j] = 0.f;

#pragma unroll
    for (int p = 0; p < P_DIM; ++p) {
      float4 av = *(const float4*)&a_s[p][te << 2];
      float4 bv = *(const float4*)&b_s[p][tn << 2];
      acc[0][0] = fmaf(av.x, bv.x, acc[0][0]);
      acc[0][1] = fmaf(av.x, bv.y, acc[0][1]);
      acc[0][2] = fmaf(av.x, bv.z, acc[0][2]);
      acc[0][3] = fmaf(av.x, bv.w, acc[0][3]);
      acc[1][0] = fmaf(av.y, bv.x, acc[1][0]);
      acc[1][1] = fmaf(av.y, bv.y, acc[1][1]);
      acc[1][2] = fmaf(av.y, bv.z, acc[1][2]);
      acc[1][3] = fmaf(av.y, bv.w, acc[1][3]);
      acc[2][0] = fmaf(av.z, bv.x, acc[2][0]);
      acc[2][1] = fmaf(av.z, bv.y, acc[2][1]);
      acc[2][2] = fmaf(av.z, bv.z, acc[2][2]);
      acc[2][3] = fmaf(av.z, bv.w, acc[2][3]);
      acc[3][0] = fmaf(av.w, bv.x, acc[3][0]);
      acc[3][1] = fmaf(av.w, bv.y, acc[3][1]);
      acc[3][2] = fmaf(av.w, bv.z, acc[3][2]);
      acc[3][3] = fmaf(av.w, bv.w, acc[3][3]);
    }
#pragma unroll
    for (int i = 0; i < 4; ++i)
#pragma unroll
      for (int j = 0; j < 4; ++j) {
        float g = fmaf(2.0f, acc[i][j], -q_s[(tn << 2) + j]);
        gm[i] = fmaxf(gm[i], g);
      }

    if (t & 1) {
#pragma unroll
      for (int i = 0; i < 4; ++i) {
        float v = gm[i];
        v = fmaxf(v, __shfl_xor(v, 1, 64));
        v = fmaxf(v, __shfl_xor(v, 2, 64));
        v = fmaxf(v, __shfl_xor(v, 4, 64));
        v = fmaxf(v, __shfl_xor(v, 8, 64));
        if (tn == 0)
          chunkg[((size_t)(b * E_DIM + e0 + (te << 2) + i)) * 32 + (ns << 2) +
                 (t >> 1)] = v;
        gm[i] = -INFINITY;
      }
    }
  }
}

// ---------------------------------------------------------------------------
// C2: per-edge sparse softmax-aggregate. One wave per edge.
// grid 1024, block 256 (4 waves).
// ---------------------------------------------------------------------------
__device__ __forceinline__ float edge_logit(const float* __restrict__ Kb,
                                            const float* __restrict__ Qb,
                                            const float* pr, float psqv,
                                            int n) {
  const float4* kp = (const float4*)(Kb + (size_t)n * P_DIM);
  float i0 = 0.f, i1 = 0.f, i2 = 0.f, i3 = 0.f;
#pragma unroll
  for (int q = 0; q < 8; ++q) {
    float4 kv = kp[q];
    i0 = fmaf(pr[4 * q + 0], kv.x, i0);
    i1 = fmaf(pr[4 * q + 1], kv.y, i1);
    i2 = fmaf(pr[4 * q + 2], kv.z, i2);
    i3 = fmaf(pr[4 * q + 3], kv.w, i3);
  }
  float inner = (i0 + i1) + (i2 + i3);
  float cost = fmaf(-2.0f, inner, psqv + Qb[n]);
  const float tau_eps = 0.1f + 1e-8f;
  return (-cost) / tau_eps;
}

__global__ __launch_bounds__(256) void k_sparse(
    const float* __restrict__ Kf, const float* __restrict__ Ksq,
    const float* __restrict__ proto, const float* __restrict__ psq,
    const float* __restrict__ VT, const float* __restrict__ chunkg,
    float* __restrict__ EF0) {
  const int tid = threadIdx.x;
  const int lane = tid & 63;
  const int eg = blockIdx.x * 4 + (tid >> 6);
  const int b = eg >> 11;
  const float* Kb = Kf + (size_t)b * N_DIM * P_DIM;
  const float* Qb = Ksq + (size_t)b * N_DIM;

  float cg = (lane < 32) ? chunkg[(size_t)eg * 32 + lane] : -INFINITY;
  float gmax = cg;
#pragma unroll
  for (int m = 1; m <= 32; m <<= 1) gmax = fmaxf(gmax, __shfl_xor(gmax, m, 64));
  unsigned long long live = __ballot(cg > gmax - 20.0f);

  float pr[P_DIM];
  const float* pe = proto + (size_t)eg * P_DIM;
#pragma unroll
  for (int p = 0; p < P_DIM; ++p) pr[p] = pe[p];
  const float psqv = psq[eg];

  float L = -INFINITY;
  unsigned long long m0 = live;
  while (m0) {
    int c = __ffsll(m0) - 1;
    m0 &= m0 - 1;
    int n = (c << 7) + lane;
    L = fmaxf(L, edge_logit(Kb, Qb, pr, psqv, n));
    L = fmaxf(L, edge_logit(Kb, Qb, pr, psqv, n + 64));
  }
#pragma unroll
  for (int m = 1; m <= 32; m <<= 1) L = fmaxf(L, __shfl_xor(L, m, 64));

  float4 acc = make_float4(0.f, 0.f, 0.f, 0.f);
  float sw = 0.f;
  const float* Vb = VT + (size_t)b * N_DIM * C_DIM;
  m0 = live;
  while (m0) {
    int c = __ffsll(m0) - 1;
    m0 &= m0 - 1;
#pragma unroll
    for (int h = 0; h < 2; ++h) {
      int n = (c << 7) + (h << 6) + lane;
      float l = edge_logit(Kb, Qb, pr, psqv, n);
      float d = l - L;
      float wgt = (d > -25.0f) ? expf(d) : 0.f;
      sw += wgt;
      unsigned long long hits = __ballot(wgt > 0.f);
      while (hits) {
        int src = __ffsll(hits) - 1;
        hits &= hits - 1;
        float wv = __shfl(wgt, src, 64);
        int nv = (c << 7) + (h << 6) + src;
        const float4 vrow =
            *(const float4*)(Vb + (size_t)nv * C_DIM + (lane << 2));
        acc.x = fmaf(wv, vrow.x, acc.x);
        acc.y = fmaf(wv, vrow.y, acc.y);
        acc.z = fmaf(wv, vrow.z, acc.z);
        acc.w = fmaf(wv, vrow.w, acc.w);
      }
    }
  }
#pragma unroll
  for (int m = 1; m <= 32; m <<= 1) sw += __shfl_xor(sw, m, 64);

  float* dst = EF0 + (size_t)eg * C_DIM + (lane << 2);
  *(float4*)dst =
      make_float4(acc.x / sw, acc.y / sw, acc.z / sw, acc.w / sw);
}

// ---------------------------------------------------------------------------
// C3: EF0t[b][c][f] = bf16(EF0[b][f][c]).  grid 256, block 256, 64x64 tiles
// ---------------------------------------------------------------------------
__global__ __launch_bounds__(256) void k_ef0t(const float* __restrict__ EF0,
                                              short* __restrict__ EF0t) {
  __shared__ short sh[64][72];
  const int tid = threadIdx.x;
  const int b = blockIdx.x >> 7;
  const int ft = (blockIdx.x >> 2) & 31;
  const int ct = blockIdx.x & 3;
  const int f0 = ft << 6, c0 = ct << 6;
#pragma unroll
  for (int i = 0; i < 4; ++i) {
    int idx = tid + i * 256;
    int f_l = idx >> 4, cc = idx & 15;
    float4 v =
        *(const float4*)&EF0[((size_t)(b * E_DIM + f0 + f_l)) * C_DIM + c0 +
                             cc * 4];
    sh[cc * 4 + 0][f_l] = (short)f2bf(v.x);
    sh[cc * 4 + 1][f_l] = (short)f2bf(v.y);
    sh[cc * 4 + 2][f_l] = (short)f2bf(v.z);
    sh[cc * 4 + 3][f_l] = (short)f2bf(v.w);
  }
  __syncthreads();
#pragma unroll
  for (int i = 0; i < 2; ++i) {
    int idx = tid + i * 256;
    int c_l = idx >> 3, ch = idx & 7;
    short8 v = *(const short8*)&sh[c_l][ch * 8];
    *(short8*)&EF0t[((size_t)(b * C_DIM + c0 + c_l)) * E_DIM + f0 + ch * 8] = v;
  }
}

// ---------------------------------------------------------------------------
// D: bf16 MFMA GEMM, full K (no split), double-buffered LDS + reg prefetch.
// out[b][c][e] = sum_f ied[b][e][f] * EF0[b][f][c].
// grid 256 (= 2b * 32et * 4ct), block 256 (4 waves). Tile 64e x 64c, BK=64,
// wave quad 32x32. LDS XOR-swizzle (byte ^= (row&7)<<4), 1 barrier/K-step.
// ---------------------------------------------------------------------------
__device__ __forceinline__ short8 lds_frag(const short* s, int row, int k) {
  int off = (((row << 6) + k) << 1) ^ ((row & 7) << 4);
  return *(const short8*)((const char*)s + off);
}
__device__ __forceinline__ void lds_put(short* s, int row, int k, short8 v) {
  int off = (((row << 6) + k) << 1) ^ ((row & 7) << 4);
  *(short8*)((char*)s + off) = v;
}

__global__ __launch_bounds__(256) void k_final_mfma(
    const short* __restrict__ Ah, const short* __restrict__ Bh,
    float* __restrict__ out) {
  __shared__ short As[2][64 * 64];
  __shared__ short Bs[2][64 * 64];
  __shared__ float Cs[64][68];

  const int tid = threadIdx.x;
  const int lane = tid & 63;
  const int w = tid >> 6;
  const int ct = blockIdx.x & 3;
  const int et = (blockIdx.x >> 2) & 31;
  const int b = blockIdx.x >> 7;
  const int e0 = et << 6, c0 = ct << 6;

  const int we = (w >> 1) << 5;   // wave e-quadrant offset
  const int wc = (w & 1) << 5;    // wave c-quadrant offset
  const int row = tid >> 2, ch = tid & 3;

  const short* gA = Ah + ((size_t)(b * E_DIM + e0 + row)) * E_DIM;
  const short* gB = Bh + ((size_t)(b * C_DIM + c0 + row)) * E_DIM;

  f32x4 z = {0.f, 0.f, 0.f, 0.f};
  f32x4 acc00 = z, acc01 = z, acc10 = z, acc11 = z;

  // prologue: tile 0 -> LDS[0]
  {
    const short8* pa = (const short8*)(gA + ch * 16);
    const short8* pb = (const short8*)(gB + ch * 16);
    short8 a0 = pa[0], a1 = pa[1];
    short8 b0 = pb[0], b1 = pb[1];
    lds_put(As[0], row, ch * 16, a0);
    lds_put(As[0], row, ch * 16 + 8, a1);
    lds_put(Bs[0], row, ch * 16, b0);
    lds_put(Bs[0], row, ch * 16 + 8, b1);
  }
  __syncthreads();

  for (int kt = 0; kt < 32; ++kt) {
    const int cur = kt & 1;
    short8 na0, na1, nb0, nb1;
    if (kt < 31) {  // issue next-tile loads early (hide HBM under MFMA)
      const int f1 = (kt + 1) << 6;
      const short8* pa = (const short8*)(gA + f1 + ch * 16);
      const short8* pb = (const short8*)(gB + f1 + ch * 16);
      na0 = pa[0]; na1 = pa[1]; nb0 = pb[0]; nb1 = pb[1];
    }
#pragma unroll
    for (int s = 0; s < 2; ++s) {
      const int kb = (s << 5) + ((lane >> 4) << 3);
      short8 fa0 = lds_frag(As[cur], we + (lane & 15), kb);
      short8 fa1 = lds_frag(As[cur], we + 16 + (lane & 15), kb);
      short8 fb0 = lds_frag(Bs[cur], wc + (lane & 15), kb);
      short8 fb1 = lds_frag(Bs[cur], wc + 16 + (lane & 15), kb);
      acc00 = __builtin_amdgcn_mfma_f32_16x16x32_bf16(fa0, fb0, acc00, 0, 0, 0);
      acc01 = __builtin_amdgcn_mfma_f32_16x16x32_bf16(fa0, fb1, acc01, 0, 0, 0);
      acc10 = __builtin_amdgcn_mfma_f32_16x16x32_bf16(fa1, fb0, acc10, 0, 0, 0);
      acc11 = __builtin_amdgcn_mfma_f32_16x16x32_bf16(fa1, fb1, acc11, 0, 0, 0);
    }
    if (kt < 31) {  // write into the buffer last read at kt-1 (barrier-safe)
      lds_put(As[cur ^ 1], row, ch * 16, na0);
      lds_put(As[cur ^ 1], row, ch * 16 + 8, na1);
      lds_put(Bs[cur ^ 1], row, ch * 16, nb0);
      lds_put(Bs[cur ^ 1], row, ch * 16 + 8, nb1);
    }
    __syncthreads();
  }

  // epilogue: stage transposed [c][e] in LDS, then coalesced fp32 writes
  const int fr = lane & 15, fq = lane >> 4;
#pragma unroll
  for (int r = 0; r < 4; ++r) {
    Cs[wc + fr][we + fq * 4 + r] = acc00[r];
    Cs[wc + 16 + fr][we + fq * 4 + r] = acc01[r];
    Cs[wc + fr][we + 16 + fq * 4 + r] = acc10[r];
    Cs[wc + 16 + fr][we + 16 + fq * 4 + r] = acc11[r];
  }
  __syncthreads();
  {
    const int c_l = tid >> 2, cch = tid & 3;
    float* dst = out + ((size_t)(b * C_DIM + c0 + c_l)) * E_DIM + e0;
#pragma unroll
    for (int r = 0; r < 4; ++r) {
      float4 v = *(const float4*)&Cs[c_l][cch * 16 + r * 4];
      *(float4*)&dst[cch * 16 + r * 4] = v;
    }
  }
}

// ---------------------------------------------------------------------------
extern "C" void kernel_launch(void* const* d_in, const int* in_sizes, int n_in,
                              void* d_out, int out_size, void* d_ws,
                              size_t ws_size, hipStream_t stream) {
  (void)in_sizes; (void)n_in; (void)out_size; (void)ws_size;
  const float* vf  = (const float*)d_in[0];
  const float* inc = (const float*)d_in[1];
  const float* ied = (const float*)d_in[2];
  const float* pw  = (const float*)d_in[5];
  const float* gm  = (const float*)d_in[6];
  const float* bt  = (const float*)d_in[7];
  const float* mn  = (const float*)d_in[8];
  const float* vr  = (const float*)d_in[9];
  float* out = (float*)d_out;

  float* ws = (float*)d_ws;
  float* VT      = ws;                  // 2,097,152 f
  float* Kf      = VT + 2097152;        //   262,144
  float* Ksq     = Kf + 262144;         //     8,192
  float* proto1  = Ksq + 8192;          //   131,072
  float* proto   = proto1 + 131072;     //   131,072
  float* psq     = proto + 131072;      //     4,096
  float* P1p     = psq + 4096;          // 32*131,072 = 4,194,304
  float* P2p     = P1p + 4194304;       //  8*131,072 = 1,048,576
  float* EF0     = P2p + 1048576;       // 1,048,576
  float* chunkg  = EF0 + 1048576;       //   131,072
  short* ied_h   = (short*)(chunkg + 131072);            // 8,388,608 shorts
  short* EF0t    = (short*)(chunkg + 131072 + 4194304);  // 1,048,576 shorts
  // total ~47 MB

  k_proj<<<dim3(128), dim3(256), 0, stream>>>(vf, pw, gm, bt, mn, vr, Kf, Ksq);
  k_transpose<<<dim3(512), dim3(256), 0, stream>>>(vf, VT);
  k_proto1<<<dim3(256), dim3(256), 0, stream>>>(inc, Kf, P1p);
  k_red32<<<dim3(512), dim3(256), 0, stream>>>(P1p, proto1);
  k_proto2<<<dim3(256), dim3(256), 0, stream>>>(ied, proto1, P2p, ied_h);
  k_red8sq<<<dim3(512), dim3(256), 0, stream>>>(P2p, proto, psq);
  k_gmax<<<dim3(512), dim3(256), 0, stream>>>(Kf, Ksq, proto, chunkg);
  k_sparse<<<dim3(1024), dim3(256), 0, stream>>>(Kf, Ksq, proto, psq, VT,
                                                 chunkg, EF0);
  k_ef0t<<<dim3(256), dim3(256), 0, stream>>>(EF0, EF0t);
  k_final_mfma<<<dim3(256), dim3(256), 0, stream>>>(ied_h, EF0t, out);
}

// Round 12
// 134.727 us; speedup vs baseline: 1.5281x; 1.1766x over previous
//
#include <hip/hip_runtime.h>
#include <math.h>

#define BS 2
#define C_DIM 256
#define N_DIM 4096
#define E_DIM 2048
#define P_DIM 32
#define NS1 32   // n-splits for proto1
#define FS2 8    // f-splits for proto2

typedef __attribute__((ext_vector_type(8))) short short8;
typedef __attribute__((ext_vector_type(4))) float f32x4;

__device__ __forceinline__ unsigned short f2bf(float f) {
  unsigned u = __float_as_uint(f);
  return (unsigned short)((u + 0x7FFFu + ((u >> 16) & 1u)) >> 16);
}

// ---------------------------------------------------------------------------
// A: K[b][n][p] = BN(proj_w @ vf), Ksq, and Kh = bf16(K).  grid 128, block 256
// ---------------------------------------------------------------------------
__global__ __launch_bounds__(256) void k_proj(
    const float* __restrict__ vf, const float* __restrict__ pw,
    const float* __restrict__ gamma, const float* __restrict__ beta,
    const float* __restrict__ mean, const float* __restrict__ var,
    float* __restrict__ Kf, float* __restrict__ Ksq,
    short* __restrict__ Kh) {
  __shared__ float w_s[P_DIM * C_DIM];
  __shared__ float part_s[4][64][P_DIM + 1];
  __shared__ float kt_s[64][P_DIM + 1];
  __shared__ float sc_s[P_DIM], sb_s[P_DIM], sm_s[P_DIM];

  const int tid = threadIdx.x;
  const int b = blockIdx.x >> 6;
  const int n0 = (blockIdx.x & 63) << 6;

  for (int i = tid; i < P_DIM * C_DIM; i += 256) w_s[i] = pw[i];
  if (tid < P_DIM) {
    sc_s[tid] = gamma[tid] / sqrtf(var[tid] + 1e-5f);
    sb_s[tid] = beta[tid];
    sm_s[tid] = mean[tid];
  }
  __syncthreads();

  const int nl = tid & 63, cs = tid >> 6;
  const float* vbase = vf + (size_t)b * C_DIM * N_DIM + n0 + nl;
  float acc[P_DIM];
#pragma unroll
  for (int p = 0; p < P_DIM; ++p) acc[p] = 0.f;
#pragma unroll 4
  for (int cc = 0; cc < 64; ++cc) {
    int c = cs * 64 + cc;
    float v = vbase[(size_t)c * N_DIM];
    const float* wc = &w_s[c];
#pragma unroll
    for (int p = 0; p < P_DIM; ++p) acc[p] = fmaf(wc[p * C_DIM], v, acc[p]);
  }
#pragma unroll
  for (int p = 0; p < P_DIM; ++p) part_s[cs][nl][p] = acc[p];
  __syncthreads();

  for (int i = tid; i < 64 * P_DIM; i += 256) {
    int n_l = i >> 5, p = i & 31;
    float s = ((part_s[0][n_l][p] + part_s[1][n_l][p]) + part_s[2][n_l][p]) +
              part_s[3][n_l][p];
    float k = (s - sm_s[p]) * sc_s[p] + sb_s[p];
    size_t gi = ((size_t)(b * N_DIM + n0 + n_l)) * P_DIM + p;
    Kf[gi] = k;
    Kh[gi] = (short)f2bf(k);
    kt_s[n_l][p] = k;
  }
  __syncthreads();
  if (tid < 64) {
    float q = 0.f;
#pragma unroll
    for (int p = 0; p < P_DIM; ++p) q = fmaf(kt_s[tid][p], kt_s[tid][p], q);
    Ksq[b * N_DIM + n0 + tid] = q;
  }
}

// ---------------------------------------------------------------------------
// A2: VT[b][n][c] = vf[b][c][n].  grid 512, block 256
// ---------------------------------------------------------------------------
__global__ __launch_bounds__(256) void k_transpose(const float* __restrict__ vf,
                                                   float* __restrict__ VT) {
  __shared__ float t_s[64][65];
  const int tid = threadIdx.x;
  const int b = blockIdx.x >> 8;
  const int n0 = ((blockIdx.x >> 2) & 63) << 6;
  const int c0 = (blockIdx.x & 3) << 6;
  const float* src = vf + (size_t)b * C_DIM * N_DIM;
#pragma unroll
  for (int i = 0; i < 16; ++i) {
    int idx = tid + i * 256;
    int n_l = idx & 63, c_l = idx >> 6;
    t_s[c_l][n_l] = src[(size_t)(c0 + c_l) * N_DIM + n0 + n_l];
  }
  __syncthreads();
  float* dst = VT + (size_t)b * N_DIM * C_DIM;
#pragma unroll
  for (int i = 0; i < 16; ++i) {
    int idx = tid + i * 256;
    int c_l = idx & 63, n_l = idx >> 6;
    dst[(size_t)(n0 + n_l) * C_DIM + c0 + c_l] = t_s[c_l][n_l];
  }
}

// ---------------------------------------------------------------------------
// B1: P1part[ns][b][e][p] = sum_{n in 128-chunk} inc[b][n][e]*K[b][n][p]
// grid 256 (= bs * 4 etiles(512e) * 32 nsplits), block 256, 2 e per thread.
// ---------------------------------------------------------------------------
__global__ __launch_bounds__(256) void k_proto1(const float* __restrict__ inc,
                                                const float* __restrict__ Kf,
                                                float* __restrict__ part) {
  __shared__ float k_s[64][P_DIM];
  const int tid = threadIdx.x;
  const int b = blockIdx.x >> 7;
  const int et = (blockIdx.x >> 5) & 3;
  const int ns = blockIdx.x & 31;
  const int e0 = et << 9;
  const int nbase = ns << 7;

  float acc0[P_DIM], acc1[P_DIM];
#pragma unroll
  for (int p = 0; p < P_DIM; ++p) { acc0[p] = 0.f; acc1[p] = 0.f; }

  for (int nt = 0; nt < 2; ++nt) {
    int n0 = nbase + nt * 64;
#pragma unroll
    for (int i = 0; i < 8; ++i) {
      int idx = tid + i * 256;
      ((float*)k_s)[idx] = Kf[((size_t)(b * N_DIM + n0)) * P_DIM + idx];
    }
    __syncthreads();
#pragma unroll 8
    for (int nn = 0; nn < 64; ++nn) {
      const float* irow = inc + ((size_t)(b * N_DIM + n0 + nn)) * E_DIM + e0;
      float va = irow[tid];
      float vb = irow[tid + 256];
      const float4* kv4 = (const float4*)k_s[nn];
#pragma unroll
      for (int q = 0; q < 8; ++q) {
        float4 kv = kv4[q];
        acc0[4 * q + 0] = fmaf(va, kv.x, acc0[4 * q + 0]);
        acc0[4 * q + 1] = fmaf(va, kv.y, acc0[4 * q + 1]);
        acc0[4 * q + 2] = fmaf(va, kv.z, acc0[4 * q + 2]);
        acc0[4 * q + 3] = fmaf(va, kv.w, acc0[4 * q + 3]);
        acc1[4 * q + 0] = fmaf(vb, kv.x, acc1[4 * q + 0]);
        acc1[4 * q + 1] = fmaf(vb, kv.y, acc1[4 * q + 1]);
        acc1[4 * q + 2] = fmaf(vb, kv.z, acc1[4 * q + 2]);
        acc1[4 * q + 3] = fmaf(vb, kv.w, acc1[4 * q + 3]);
      }
    }
    __syncthreads();
  }
  float* dst0 = part + (size_t)ns * (BS * E_DIM * P_DIM) +
                ((size_t)(b * E_DIM + e0 + tid)) * P_DIM;
  float* dst1 = dst0 + 256 * P_DIM;
#pragma unroll
  for (int q = 0; q < 8; ++q) {
    ((float4*)dst0)[q] = make_float4(acc0[4 * q + 0], acc0[4 * q + 1],
                                     acc0[4 * q + 2], acc0[4 * q + 3]);
    ((float4*)dst1)[q] = make_float4(acc1[4 * q + 0], acc1[4 * q + 1],
                                     acc1[4 * q + 2], acc1[4 * q + 3]);
  }
}

// ---------------------------------------------------------------------------
// B2: proto1 = sum of 32 partials.  grid 512, block 256
// ---------------------------------------------------------------------------
__global__ __launch_bounds__(256) void k_red32(const float* __restrict__ part,
                                               float* __restrict__ outp) {
  int g = blockIdx.x * 256 + threadIdx.x;
  float v = 0.f;
#pragma unroll
  for (int s = 0; s < NS1; ++s)
    v += part[(size_t)s * (BS * E_DIM * P_DIM) + g];
  outp[g] = v;
}

// ---------------------------------------------------------------------------
// B3: P2part[fs][b][e][p] = sum_{f in 256-chunk} ied[b][e][f]*proto1[b][f][p]
// grid 256, block 256, [2e][8p]/thread. ALSO emits ied_h = bf16(ied).
// ---------------------------------------------------------------------------
__global__ __launch_bounds__(256) void k_proto2(const float* __restrict__ ied,
                                                const float* __restrict__ proto1,
                                                float* __restrict__ part,
                                                short* __restrict__ ied_h) {
  __shared__ float inv_s[128][33];
  __shared__ float p1_s[32][P_DIM];
  const int tid = threadIdx.x;
  const int b = blockIdx.x >> 7;
  const int et = (blockIdx.x >> 3) & 15;
  const int fs = blockIdx.x & 7;
  const int e0 = et << 7;
  const int fbase = fs << 8;
  const int e_l = tid & 63, pg = tid >> 6;

  float acc0[8], acc1[8];
#pragma unroll
  for (int q = 0; q < 8; ++q) { acc0[q] = 0.f; acc1[q] = 0.f; }

  for (int ft = 0; ft < 8; ++ft) {
    int f0 = fbase + ft * 32;
    __syncthreads();
#pragma unroll
    for (int i = 0; i < 16; ++i) {
      int idx = tid + i * 256;
      int e_r = idx >> 5, f_l = idx & 31;
      size_t gidx = ((size_t)(b * E_DIM + e0 + e_r)) * E_DIM + f0 + f_l;
      float v = ied[gidx];
      inv_s[e_r][f_l] = v;
      ied_h[gidx] = (short)f2bf(v);
    }
#pragma unroll
    for (int i = 0; i < 4; ++i) {
      int idx = tid + i * 256;
      ((float*)p1_s)[idx] = proto1[((size_t)(b * E_DIM + f0)) * P_DIM + idx];
    }
    __syncthreads();
#pragma unroll
    for (int ff = 0; ff < 32; ++ff) {
      float a0 = inv_s[e_l][ff];
      float a1 = inv_s[e_l + 64][ff];
      const float4* pv4 = (const float4*)&p1_s[ff][pg * 8];
      float4 pv0 = pv4[0], pv1 = pv4[1];
      acc0[0] = fmaf(a0, pv0.x, acc0[0]);
      acc0[1] = fmaf(a0, pv0.y, acc0[1]);
      acc0[2] = fmaf(a0, pv0.z, acc0[2]);
      acc0[3] = fmaf(a0, pv0.w, acc0[3]);
      acc0[4] = fmaf(a0, pv1.x, acc0[4]);
      acc0[5] = fmaf(a0, pv1.y, acc0[5]);
      acc0[6] = fmaf(a0, pv1.z, acc0[6]);
      acc0[7] = fmaf(a0, pv1.w, acc0[7]);
      acc1[0] = fmaf(a1, pv0.x, acc1[0]);
      acc1[1] = fmaf(a1, pv0.y, acc1[1]);
      acc1[2] = fmaf(a1, pv0.z, acc1[2]);
      acc1[3] = fmaf(a1, pv0.w, acc1[3]);
      acc1[4] = fmaf(a1, pv1.x, acc1[4]);
      acc1[5] = fmaf(a1, pv1.y, acc1[5]);
      acc1[6] = fmaf(a1, pv1.z, acc1[6]);
      acc1[7] = fmaf(a1, pv1.w, acc1[7]);
    }
  }
  float* dst0 = part + (size_t)fs * (BS * E_DIM * P_DIM) +
                ((size_t)(b * E_DIM + e0 + e_l)) * P_DIM + pg * 8;
  float* dst1 = dst0 + 64 * P_DIM;
  ((float4*)dst0)[0] = make_float4(acc0[0], acc0[1], acc0[2], acc0[3]);
  ((float4*)dst0)[1] = make_float4(acc0[4], acc0[5], acc0[6], acc0[7]);
  ((float4*)dst1)[0] = make_float4(acc1[0], acc1[1], acc1[2], acc1[3]);
  ((float4*)dst1)[1] = make_float4(acc1[4], acc1[5], acc1[6], acc1[7]);
}

// ---------------------------------------------------------------------------
// B4: proto = sum of 8 partials; proto_sq; proto_h = bf16(proto).
// grid 512, block 256
// ---------------------------------------------------------------------------
__global__ __launch_bounds__(256) void k_red8sq(const float* __restrict__ part,
                                                float* __restrict__ proto,
                                                float* __restrict__ psq,
                                                short* __restrict__ Ph) {
  int g = blockIdx.x * 256 + threadIdx.x;
  float v = 0.f;
#pragma unroll
  for (int s = 0; s < FS2; ++s)
    v += part[(size_t)s * (BS * E_DIM * P_DIM) + g];
  proto[g] = v;
  Ph[g] = (short)f2bf(v);
  float q = v * v;
#pragma unroll
  for (int m = 1; m <= 16; m <<= 1) q += __shfl_xor(q, m, 64);
  if ((threadIdx.x & 31) == 0) psq[g >> 5] = q;
}

// ---------------------------------------------------------------------------
// C1: SCREENING chunk-max via bf16 MFMA: chunkg[e][ch] ~ max_n 2<p_e,K_n>-ksq_n
// (approximate — k_sparse's widened threshold absorbs bf16 error; exact fp32
//  logit path in k_sparse is unchanged.)
// grid 2048 (= bs * 32 etiles(64e) * 32 chunks), block 256 (4 waves x 16e).
// Operands straight from L2 (proto 256KB, K 512KB per batch). No LDS.
// A/B frag layout identical to the validated k_final_mfma pattern.
// ---------------------------------------------------------------------------
__global__ __launch_bounds__(256) void k_gmax_mfma(
    const short* __restrict__ Kh, const float* __restrict__ Ksq,
    const short* __restrict__ Ph, float* __restrict__ chunkg) {
  const int tid = threadIdx.x;
  const int lane = tid & 63;
  const int w = tid >> 6;
  const int b = blockIdx.x >> 10;
  const int et = (blockIdx.x >> 5) & 31;
  const int ch = blockIdx.x & 31;
  const int e0 = (et << 6) + (w << 4);  // this wave's 16 e-rows
  const int n0 = ch << 7;

  const int r15 = lane & 15, q = lane >> 4;

  // A frag: proto rows e0+r15, k = q*8 .. q*8+7 (contiguous in P)
  short8 fa =
      *(const short8*)&Ph[((size_t)(b * E_DIM + e0 + r15)) * P_DIM + q * 8];

  f32x4 z = {0.f, 0.f, 0.f, 0.f};
  f32x4 ac0 = z, ac1 = z, ac2 = z, ac3 = z, ac4 = z, ac5 = z, ac6 = z, ac7 = z;
  const short* kb = Kh + ((size_t)(b * N_DIM + n0 + r15)) * P_DIM + q * 8;
#define GSTEP(S, AC)                                                     \
  {                                                                      \
    short8 fb = *(const short8*)(kb + (size_t)(S * 16) * P_DIM);         \
    AC = __builtin_amdgcn_mfma_f32_16x16x32_bf16(fa, fb, AC, 0, 0, 0);   \
  }
  GSTEP(0, ac0) GSTEP(1, ac1) GSTEP(2, ac2) GSTEP(3, ac3)
  GSTEP(4, ac4) GSTEP(5, ac5) GSTEP(6, ac6) GSTEP(7, ac7)
#undef GSTEP

  const float* qsb = Ksq + (size_t)b * N_DIM + n0 + r15;
  float ks0 = qsb[0], ks1 = qsb[16], ks2 = qsb[32], ks3 = qsb[48];
  float ks4 = qsb[64], ks5 = qsb[80], ks6 = qsb[96], ks7 = qsb[112];

  // acS[r] = C[e0 + q*4 + r][n0 + S*16 + r15]
#pragma unroll
  for (int r = 0; r < 4; ++r) {
    float m = fmaf(2.0f, ac0[r], -ks0);
    m = fmaxf(m, fmaf(2.0f, ac1[r], -ks1));
    m = fmaxf(m, fmaf(2.0f, ac2[r], -ks2));
    m = fmaxf(m, fmaf(2.0f, ac3[r], -ks3));
    m = fmaxf(m, fmaf(2.0f, ac4[r], -ks4));
    m = fmaxf(m, fmaf(2.0f, ac5[r], -ks5));
    m = fmaxf(m, fmaf(2.0f, ac6[r], -ks6));
    m = fmaxf(m, fmaf(2.0f, ac7[r], -ks7));
    m = fmaxf(m, __shfl_xor(m, 1, 64));
    m = fmaxf(m, __shfl_xor(m, 2, 64));
    m = fmaxf(m, __shfl_xor(m, 4, 64));
    m = fmaxf(m, __shfl_xor(m, 8, 64));
    if (r15 == 0)
      chunkg[((size_t)(b * E_DIM + e0 + q * 4 + r)) * 32 + ch] = m;
  }
}

// ---------------------------------------------------------------------------
// C2: per-edge sparse softmax-aggregate. One wave per edge.
// grid 1024, block 256 (4 waves). Screen threshold 3000 (g-units) absorbs
// bf16 chunkg error (<=~1300 worst-case); dropped mass still exactly 0.
// ---------------------------------------------------------------------------
__device__ __forceinline__ float edge_logit(const float* __restrict__ Kb,
                                            const float* __restrict__ Qb,
                                            const float* pr, float psqv,
                                            int n) {
  const float4* kp = (const float4*)(Kb + (size_t)n * P_DIM);
  float i0 = 0.f, i1 = 0.f, i2 = 0.f, i3 = 0.f;
#pragma unroll
  for (int q = 0; q < 8; ++q) {
    float4 kv = kp[q];
    i0 = fmaf(pr[4 * q + 0], kv.x, i0);
    i1 = fmaf(pr[4 * q + 1], kv.y, i1);
    i2 = fmaf(pr[4 * q + 2], kv.z, i2);
    i3 = fmaf(pr[4 * q + 3], kv.w, i3);
  }
  float inner = (i0 + i1) + (i2 + i3);
  float cost = fmaf(-2.0f, inner, psqv + Qb[n]);
  const float tau_eps = 0.1f + 1e-8f;
  return (-cost) / tau_eps;
}

__global__ __launch_bounds__(256) void k_sparse(
    const float* __restrict__ Kf, const float* __restrict__ Ksq,
    const float* __restrict__ proto, const float* __restrict__ psq,
    const float* __restrict__ VT, const float* __restrict__ chunkg,
    float* __restrict__ EF0) {
  const int tid = threadIdx.x;
  const int lane = tid & 63;
  const int eg = blockIdx.x * 4 + (tid >> 6);
  const int b = eg >> 11;
  const float* Kb = Kf + (size_t)b * N_DIM * P_DIM;
  const float* Qb = Ksq + (size_t)b * N_DIM;

  float cg = (lane < 32) ? chunkg[(size_t)eg * 32 + lane] : -INFINITY;
  float gmax = cg;
#pragma unroll
  for (int m = 1; m <= 32; m <<= 1) gmax = fmaxf(gmax, __shfl_xor(gmax, m, 64));
  unsigned long long live = __ballot(cg > gmax - 3000.0f);

  float pr[P_DIM];
  const float* pe = proto + (size_t)eg * P_DIM;
#pragma unroll
  for (int p = 0; p < P_DIM; ++p) pr[p] = pe[p];
  const float psqv = psq[eg];

  float L = -INFINITY;
  unsigned long long m0 = live;
  while (m0) {
    int c = __ffsll(m0) - 1;
    m0 &= m0 - 1;
    int n = (c << 7) + lane;
    L = fmaxf(L, edge_logit(Kb, Qb, pr, psqv, n));
    L = fmaxf(L, edge_logit(Kb, Qb, pr, psqv, n + 64));
  }
#pragma unroll
  for (int m = 1; m <= 32; m <<= 1) L = fmaxf(L, __shfl_xor(L, m, 64));

  float4 acc = make_float4(0.f, 0.f, 0.f, 0.f);
  float sw = 0.f;
  const float* Vb = VT + (size_t)b * N_DIM * C_DIM;
  m0 = live;
  while (m0) {
    int c = __ffsll(m0) - 1;
    m0 &= m0 - 1;
#pragma unroll
    for (int h = 0; h < 2; ++h) {
      int n = (c << 7) + (h << 6) + lane;
      float l = edge_logit(Kb, Qb, pr, psqv, n);
      float d = l - L;
      float wgt = (d > -25.0f) ? expf(d) : 0.f;
      sw += wgt;
      unsigned long long hits = __ballot(wgt > 0.f);
      while (hits) {
        int src = __ffsll(hits) - 1;
        hits &= hits - 1;
        float wv = __shfl(wgt, src, 64);
        int nv = (c << 7) + (h << 6) + src;
        const float4 vrow =
            *(const float4*)(Vb + (size_t)nv * C_DIM + (lane << 2));
        acc.x = fmaf(wv, vrow.x, acc.x);
        acc.y = fmaf(wv, vrow.y, acc.y);
        acc.z = fmaf(wv, vrow.z, acc.z);
        acc.w = fmaf(wv, vrow.w, acc.w);
      }
    }
  }
#pragma unroll
  for (int m = 1; m <= 32; m <<= 1) sw += __shfl_xor(sw, m, 64);

  float* dst = EF0 + (size_t)eg * C_DIM + (lane << 2);
  *(float4*)dst =
      make_float4(acc.x / sw, acc.y / sw, acc.z / sw, acc.w / sw);
}

// ---------------------------------------------------------------------------
// C3: EF0t[b][c][f] = bf16(EF0[b][f][c]).  grid 256, block 256, 64x64 tiles
// ---------------------------------------------------------------------------
__global__ __launch_bounds__(256) void k_ef0t(const float* __restrict__ EF0,
                                              short* __restrict__ EF0t) {
  __shared__ short sh[64][72];
  const int tid = threadIdx.x;
  const int b = blockIdx.x >> 7;
  const int ft = (blockIdx.x >> 2) & 31;
  const int ct = blockIdx.x & 3;
  const int f0 = ft << 6, c0 = ct << 6;
#pragma unroll
  for (int i = 0; i < 4; ++i) {
    int idx = tid + i * 256;
    int f_l = idx >> 4, cc = idx & 15;
    float4 v =
        *(const float4*)&EF0[((size_t)(b * E_DIM + f0 + f_l)) * C_DIM + c0 +
                             cc * 4];
    sh[cc * 4 + 0][f_l] = (short)f2bf(v.x);
    sh[cc * 4 + 1][f_l] = (short)f2bf(v.y);
    sh[cc * 4 + 2][f_l] = (short)f2bf(v.z);
    sh[cc * 4 + 3][f_l] = (short)f2bf(v.w);
  }
  __syncthreads();
#pragma unroll
  for (int i = 0; i < 2; ++i) {
    int idx = tid + i * 256;
    int c_l = idx >> 3, ch = idx & 7;
    short8 v = *(const short8*)&sh[c_l][ch * 8];
    *(short8*)&EF0t[((size_t)(b * C_DIM + c0 + c_l)) * E_DIM + f0 + ch * 8] = v;
  }
}

// ---------------------------------------------------------------------------
// D: bf16 MFMA GEMM, full K (no split), double-buffered LDS + reg prefetch.
// out[b][c][e] = sum_f ied[b][e][f] * EF0[b][f][c].
// grid 256 (= 2b * 32et * 4ct), block 256 (4 waves). Tile 64e x 64c, BK=64,
// wave quad 32x32. LDS XOR-swizzle (byte ^= (row&7)<<4), 1 barrier/K-step.
// ---------------------------------------------------------------------------
__device__ __forceinline__ short8 lds_frag(const short* s, int row, int k) {
  int off = (((row << 6) + k) << 1) ^ ((row & 7) << 4);
  return *(const short8*)((const char*)s + off);
}
__device__ __forceinline__ void lds_put(short* s, int row, int k, short8 v) {
  int off = (((row << 6) + k) << 1) ^ ((row & 7) << 4);
  *(short8*)((char*)s + off) = v;
}

__global__ __launch_bounds__(256) void k_final_mfma(
    const short* __restrict__ Ah, const short* __restrict__ Bh,
    float* __restrict__ out) {
  __shared__ short As[2][64 * 64];
  __shared__ short Bs[2][64 * 64];
  __shared__ float Cs[64][68];

  const int tid = threadIdx.x;
  const int lane = tid & 63;
  const int w = tid >> 6;
  const int ct = blockIdx.x & 3;
  const int et = (blockIdx.x >> 2) & 31;
  const int b = blockIdx.x >> 7;
  const int e0 = et << 6, c0 = ct << 6;

  const int we = (w >> 1) << 5;   // wave e-quadrant offset
  const int wc = (w & 1) << 5;    // wave c-quadrant offset
  const int row = tid >> 2, ch = tid & 3;

  const short* gA = Ah + ((size_t)(b * E_DIM + e0 + row)) * E_DIM;
  const short* gB = Bh + ((size_t)(b * C_DIM + c0 + row)) * E_DIM;

  f32x4 z = {0.f, 0.f, 0.f, 0.f};
  f32x4 acc00 = z, acc01 = z, acc10 = z, acc11 = z;

  // prologue: tile 0 -> LDS[0]
  {
    const short8* pa = (const short8*)(gA + ch * 16);
    const short8* pb = (const short8*)(gB + ch * 16);
    short8 a0 = pa[0], a1 = pa[1];
    short8 b0 = pb[0], b1 = pb[1];
    lds_put(As[0], row, ch * 16, a0);
    lds_put(As[0], row, ch * 16 + 8, a1);
    lds_put(Bs[0], row, ch * 16, b0);
    lds_put(Bs[0], row, ch * 16 + 8, b1);
  }
  __syncthreads();

  for (int kt = 0; kt < 32; ++kt) {
    const int cur = kt & 1;
    short8 na0, na1, nb0, nb1;
    if (kt < 31) {  // issue next-tile loads early (hide HBM under MFMA)
      const int f1 = (kt + 1) << 6;
      const short8* pa = (const short8*)(gA + f1 + ch * 16);
      const short8* pb = (const short8*)(gB + f1 + ch * 16);
      na0 = pa[0]; na1 = pa[1]; nb0 = pb[0]; nb1 = pb[1];
    }
#pragma unroll
    for (int s = 0; s < 2; ++s) {
      const int kb = (s << 5) + ((lane >> 4) << 3);
      short8 fa0 = lds_frag(As[cur], we + (lane & 15), kb);
      short8 fa1 = lds_frag(As[cur], we + 16 + (lane & 15), kb);
      short8 fb0 = lds_frag(Bs[cur], wc + (lane & 15), kb);
      short8 fb1 = lds_frag(Bs[cur], wc + 16 + (lane & 15), kb);
      acc00 = __builtin_amdgcn_mfma_f32_16x16x32_bf16(fa0, fb0, acc00, 0, 0, 0);
      acc01 = __builtin_amdgcn_mfma_f32_16x16x32_bf16(fa0, fb1, acc01, 0, 0, 0);
      acc10 = __builtin_amdgcn_mfma_f32_16x16x32_bf16(fa1, fb0, acc10, 0, 0, 0);
      acc11 = __builtin_amdgcn_mfma_f32_16x16x32_bf16(fa1, fb1, acc11, 0, 0, 0);
    }
    if (kt < 31) {  // write into the buffer last read at kt-1 (barrier-safe)
      lds_put(As[cur ^ 1], row, ch * 16, na0);
      lds_put(As[cur ^ 1], row, ch * 16 + 8, na1);
      lds_put(Bs[cur ^ 1], row, ch * 16, nb0);
      lds_put(Bs[cur ^ 1], row, ch * 16 + 8, nb1);
    }
    __syncthreads();
  }

  // epilogue: stage transposed [c][e] in LDS, then coalesced fp32 writes
  const int fr = lane & 15, fq = lane >> 4;
#pragma unroll
  for (int r = 0; r < 4; ++r) {
    Cs[wc + fr][we + fq * 4 + r] = acc00[r];
    Cs[wc + 16 + fr][we + fq * 4 + r] = acc01[r];
    Cs[wc + fr][we + 16 + fq * 4 + r] = acc10[r];
    Cs[wc + 16 + fr][we + 16 + fq * 4 + r] = acc11[r];
  }
  __syncthreads();
  {
    const int c_l = tid >> 2, cch = tid & 3;
    float* dst = out + ((size_t)(b * C_DIM + c0 + c_l)) * E_DIM + e0;
#pragma unroll
    for (int r = 0; r < 4; ++r) {
      float4 v = *(const float4*)&Cs[c_l][cch * 16 + r * 4];
      *(float4*)&dst[cch * 16 + r * 4] = v;
    }
  }
}

// ---------------------------------------------------------------------------
extern "C" void kernel_launch(void* const* d_in, const int* in_sizes, int n_in,
                              void* d_out, int out_size, void* d_ws,
                              size_t ws_size, hipStream_t stream) {
  (void)in_sizes; (void)n_in; (void)out_size; (void)ws_size;
  const float* vf  = (const float*)d_in[0];
  const float* inc = (const float*)d_in[1];
  const float* ied = (const float*)d_in[2];
  const float* pw  = (const float*)d_in[5];
  const float* gm  = (const float*)d_in[6];
  const float* bt  = (const float*)d_in[7];
  const float* mn  = (const float*)d_in[8];
  const float* vr  = (const float*)d_in[9];
  float* out = (float*)d_out;

  float* ws = (float*)d_ws;
  float* VT      = ws;                  // 2,097,152 f
  float* Kf      = VT + 2097152;        //   262,144
  float* Ksq     = Kf + 262144;         //     8,192
  float* proto1  = Ksq + 8192;          //   131,072
  float* proto   = proto1 + 131072;     //   131,072
  float* psq     = proto + 131072;      //     4,096
  float* P1p     = psq + 4096;          // 32*131,072 = 4,194,304
  float* P2p     = P1p + 4194304;       //  8*131,072 = 1,048,576
  float* EF0     = P2p + 1048576;       // 1,048,576
  float* chunkg  = EF0 + 1048576;       //   131,072
  short* ied_h   = (short*)(chunkg + 131072);            // 8,388,608 shorts
  short* EF0t    = (short*)(chunkg + 131072 + 4194304);  // 1,048,576 shorts
  short* Kh      = EF0t + 1048576;                       //   262,144 shorts
  short* Ph      = Kh + 262144;                          //   131,072 shorts
  // total ~48 MB

  k_proj<<<dim3(128), dim3(256), 0, stream>>>(vf, pw, gm, bt, mn, vr, Kf, Ksq,
                                              Kh);
  k_transpose<<<dim3(512), dim3(256), 0, stream>>>(vf, VT);
  k_proto1<<<dim3(256), dim3(256), 0, stream>>>(inc, Kf, P1p);
  k_red32<<<dim3(512), dim3(256), 0, stream>>>(P1p, proto1);
  k_proto2<<<dim3(256), dim3(256), 0, stream>>>(ied, proto1, P2p, ied_h);
  k_red8sq<<<dim3(512), dim3(256), 0, stream>>>(P2p, proto, psq, Ph);
  k_gmax_mfma<<<dim3(2048), dim3(256), 0, stream>>>(Kh, Ksq, Ph, chunkg);
  k_sparse<<<dim3(1024), dim3(256), 0, stream>>>(Kf, Ksq, proto, psq, VT,
                                                 chunkg, EF0);
  k_ef0t<<<dim3(256), dim3(256), 0, stream>>>(EF0, EF0t);
  k_final_mfma<<<dim3(256), dim3(256), 0, stream>>>(ied_h, EF0t, out);
}

// Round 13
// 133.095 us; speedup vs baseline: 1.5468x; 1.0123x over previous
//
#include <hip/hip_runtime.h>
#include <math.h>

#define BS 2
#define C_DIM 256
#define N_DIM 4096
#define E_DIM 2048
#define P_DIM 32
#define NS1 32   // n-splits for proto1
#define FS2 8    // f-splits for proto2

typedef __attribute__((ext_vector_type(8))) short short8;
typedef __attribute__((ext_vector_type(4))) float f32x4;

__device__ __forceinline__ unsigned short f2bf(float f) {
  unsigned u = __float_as_uint(f);
  return (unsigned short)((u + 0x7FFFu + ((u >> 16) & 1u)) >> 16);
}

// ---------------------------------------------------------------------------
// A: K = BN(proj_w @ vf), Ksq, Kh = bf16(K), AND VT[b][n][c] = vf[b][c][n]
// (transpose fused: vf slice is L2-hot after phase 1).  grid 128, block 256
// ---------------------------------------------------------------------------
__global__ __launch_bounds__(256) void k_proj(
    const float* __restrict__ vf, const float* __restrict__ pw,
    const float* __restrict__ gamma, const float* __restrict__ beta,
    const float* __restrict__ mean, const float* __restrict__ var,
    float* __restrict__ Kf, float* __restrict__ Ksq,
    short* __restrict__ Kh, float* __restrict__ VT) {
  __shared__ float w_s[P_DIM * C_DIM];
  __shared__ float part_s[4][64][P_DIM + 1];
  __shared__ float kt_s[64][P_DIM + 1];
  __shared__ float t2_s[64][65];
  __shared__ float sc_s[P_DIM], sb_s[P_DIM], sm_s[P_DIM];

  const int tid = threadIdx.x;
  const int b = blockIdx.x >> 6;
  const int n0 = (blockIdx.x & 63) << 6;

  for (int i = tid; i < P_DIM * C_DIM; i += 256) w_s[i] = pw[i];
  if (tid < P_DIM) {
    sc_s[tid] = gamma[tid] / sqrtf(var[tid] + 1e-5f);
    sb_s[tid] = beta[tid];
    sm_s[tid] = mean[tid];
  }
  __syncthreads();

  const int nl = tid & 63, cs = tid >> 6;
  const float* vbase = vf + (size_t)b * C_DIM * N_DIM + n0 + nl;
  float acc[P_DIM];
#pragma unroll
  for (int p = 0; p < P_DIM; ++p) acc[p] = 0.f;
#pragma unroll 4
  for (int cc = 0; cc < 64; ++cc) {
    int c = cs * 64 + cc;
    float v = vbase[(size_t)c * N_DIM];
    const float* wc = &w_s[c];
#pragma unroll
    for (int p = 0; p < P_DIM; ++p) acc[p] = fmaf(wc[p * C_DIM], v, acc[p]);
  }
#pragma unroll
  for (int p = 0; p < P_DIM; ++p) part_s[cs][nl][p] = acc[p];
  __syncthreads();

  for (int i = tid; i < 64 * P_DIM; i += 256) {
    int n_l = i >> 5, p = i & 31;
    float s = ((part_s[0][n_l][p] + part_s[1][n_l][p]) + part_s[2][n_l][p]) +
              part_s[3][n_l][p];
    float k = (s - sm_s[p]) * sc_s[p] + sb_s[p];
    size_t gi = ((size_t)(b * N_DIM + n0 + n_l)) * P_DIM + p;
    Kf[gi] = k;
    Kh[gi] = (short)f2bf(k);
    kt_s[n_l][p] = k;
  }
  __syncthreads();
  if (tid < 64) {
    float q = 0.f;
#pragma unroll
    for (int p = 0; p < P_DIM; ++p) q = fmaf(kt_s[tid][p], kt_s[tid][p], q);
    Ksq[b * N_DIM + n0 + tid] = q;
  }

  // ---- phase 2: transpose this block's 64-n strip of vf into VT (L2-hot)
  const float* src = vf + (size_t)b * C_DIM * N_DIM;
  float* dst = VT + (size_t)b * N_DIM * C_DIM;
  for (int ct = 0; ct < 4; ++ct) {
    const int c0 = ct << 6;
    __syncthreads();
#pragma unroll
    for (int i = 0; i < 16; ++i) {
      int idx = tid + i * 256;
      int c_l = idx >> 6, n_l2 = idx & 63;
      t2_s[c_l][n_l2] = src[(size_t)(c0 + c_l) * N_DIM + n0 + n_l2];
    }
    __syncthreads();
#pragma unroll
    for (int i = 0; i < 16; ++i) {
      int idx = tid + i * 256;
      int c_l = idx & 63, n_l2 = idx >> 6;
      dst[(size_t)(n0 + n_l2) * C_DIM + c0 + c_l] = t2_s[c_l][n_l2];
    }
  }
}

// ---------------------------------------------------------------------------
// B1: P1part[ns][b][e][p] = sum_{n in 128-chunk} inc[b][n][e]*K[b][n][p]
// grid 256 (= bs * 4 etiles(512e) * 32 nsplits), block 256, 2 e per thread.
// ---------------------------------------------------------------------------
__global__ __launch_bounds__(256) void k_proto1(const float* __restrict__ inc,
                                                const float* __restrict__ Kf,
                                                float* __restrict__ part) {
  __shared__ float k_s[64][P_DIM];
  const int tid = threadIdx.x;
  const int b = blockIdx.x >> 7;
  const int et = (blockIdx.x >> 5) & 3;
  const int ns = blockIdx.x & 31;
  const int e0 = et << 9;
  const int nbase = ns << 7;

  float acc0[P_DIM], acc1[P_DIM];
#pragma unroll
  for (int p = 0; p < P_DIM; ++p) { acc0[p] = 0.f; acc1[p] = 0.f; }

  for (int nt = 0; nt < 2; ++nt) {
    int n0 = nbase + nt * 64;
#pragma unroll
    for (int i = 0; i < 8; ++i) {
      int idx = tid + i * 256;
      ((float*)k_s)[idx] = Kf[((size_t)(b * N_DIM + n0)) * P_DIM + idx];
    }
    __syncthreads();
#pragma unroll 8
    for (int nn = 0; nn < 64; ++nn) {
      const float* irow = inc + ((size_t)(b * N_DIM + n0 + nn)) * E_DIM + e0;
      float va = irow[tid];
      float vb = irow[tid + 256];
      const float4* kv4 = (const float4*)k_s[nn];
#pragma unroll
      for (int q = 0; q < 8; ++q) {
        float4 kv = kv4[q];
        acc0[4 * q + 0] = fmaf(va, kv.x, acc0[4 * q + 0]);
        acc0[4 * q + 1] = fmaf(va, kv.y, acc0[4 * q + 1]);
        acc0[4 * q + 2] = fmaf(va, kv.z, acc0[4 * q + 2]);
        acc0[4 * q + 3] = fmaf(va, kv.w, acc0[4 * q + 3]);
        acc1[4 * q + 0] = fmaf(vb, kv.x, acc1[4 * q + 0]);
        acc1[4 * q + 1] = fmaf(vb, kv.y, acc1[4 * q + 1]);
        acc1[4 * q + 2] = fmaf(vb, kv.z, acc1[4 * q + 2]);
        acc1[4 * q + 3] = fmaf(vb, kv.w, acc1[4 * q + 3]);
      }
    }
    __syncthreads();
  }
  float* dst0 = part + (size_t)ns * (BS * E_DIM * P_DIM) +
                ((size_t)(b * E_DIM + e0 + tid)) * P_DIM;
  float* dst1 = dst0 + 256 * P_DIM;
#pragma unroll
  for (int q = 0; q < 8; ++q) {
    ((float4*)dst0)[q] = make_float4(acc0[4 * q + 0], acc0[4 * q + 1],
                                     acc0[4 * q + 2], acc0[4 * q + 3]);
    ((float4*)dst1)[q] = make_float4(acc1[4 * q + 0], acc1[4 * q + 1],
                                     acc1[4 * q + 2], acc1[4 * q + 3]);
  }
}

// ---------------------------------------------------------------------------
// B2: proto1 = sum of 32 partials.  grid 512, block 256
// ---------------------------------------------------------------------------
__global__ __launch_bounds__(256) void k_red32(const float* __restrict__ part,
                                               float* __restrict__ outp) {
  int g = blockIdx.x * 256 + threadIdx.x;
  float v = 0.f;
#pragma unroll
  for (int s = 0; s < NS1; ++s)
    v += part[(size_t)s * (BS * E_DIM * P_DIM) + g];
  outp[g] = v;
}

// ---------------------------------------------------------------------------
// B3: P2part[fs][b][e][p] = sum_{f in 256-chunk} ied[b][e][f]*proto1[b][f][p]
// grid 256, block 256, [2e][8p]/thread. ALSO emits ied_h = bf16(ied).
// ---------------------------------------------------------------------------
__global__ __launch_bounds__(256) void k_proto2(const float* __restrict__ ied,
                                                const float* __restrict__ proto1,
                                                float* __restrict__ part,
                                                short* __restrict__ ied_h) {
  __shared__ float inv_s[128][33];
  __shared__ float p1_s[32][P_DIM];
  const int tid = threadIdx.x;
  const int b = blockIdx.x >> 7;
  const int et = (blockIdx.x >> 3) & 15;
  const int fs = blockIdx.x & 7;
  const int e0 = et << 7;
  const int fbase = fs << 8;
  const int e_l = tid & 63, pg = tid >> 6;

  float acc0[8], acc1[8];
#pragma unroll
  for (int q = 0; q < 8; ++q) { acc0[q] = 0.f; acc1[q] = 0.f; }

  for (int ft = 0; ft < 8; ++ft) {
    int f0 = fbase + ft * 32;
    __syncthreads();
#pragma unroll
    for (int i = 0; i < 16; ++i) {
      int idx = tid + i * 256;
      int e_r = idx >> 5, f_l = idx & 31;
      size_t gidx = ((size_t)(b * E_DIM + e0 + e_r)) * E_DIM + f0 + f_l;
      float v = ied[gidx];
      inv_s[e_r][f_l] = v;
      ied_h[gidx] = (short)f2bf(v);
    }
#pragma unroll
    for (int i = 0; i < 4; ++i) {
      int idx = tid + i * 256;
      ((float*)p1_s)[idx] = proto1[((size_t)(b * E_DIM + f0)) * P_DIM + idx];
    }
    __syncthreads();
#pragma unroll
    for (int ff = 0; ff < 32; ++ff) {
      float a0 = inv_s[e_l][ff];
      float a1 = inv_s[e_l + 64][ff];
      const float4* pv4 = (const float4*)&p1_s[ff][pg * 8];
      float4 pv0 = pv4[0], pv1 = pv4[1];
      acc0[0] = fmaf(a0, pv0.x, acc0[0]);
      acc0[1] = fmaf(a0, pv0.y, acc0[1]);
      acc0[2] = fmaf(a0, pv0.z, acc0[2]);
      acc0[3] = fmaf(a0, pv0.w, acc0[3]);
      acc0[4] = fmaf(a0, pv1.x, acc0[4]);
      acc0[5] = fmaf(a0, pv1.y, acc0[5]);
      acc0[6] = fmaf(a0, pv1.z, acc0[6]);
      acc0[7] = fmaf(a0, pv1.w, acc0[7]);
      acc1[0] = fmaf(a1, pv0.x, acc1[0]);
      acc1[1] = fmaf(a1, pv0.y, acc1[1]);
      acc1[2] = fmaf(a1, pv0.z, acc1[2]);
      acc1[3] = fmaf(a1, pv0.w, acc1[3]);
      acc1[4] = fmaf(a1, pv1.x, acc1[4]);
      acc1[5] = fmaf(a1, pv1.y, acc1[5]);
      acc1[6] = fmaf(a1, pv1.z, acc1[6]);
      acc1[7] = fmaf(a1, pv1.w, acc1[7]);
    }
  }
  float* dst0 = part + (size_t)fs * (BS * E_DIM * P_DIM) +
                ((size_t)(b * E_DIM + e0 + e_l)) * P_DIM + pg * 8;
  float* dst1 = dst0 + 64 * P_DIM;
  ((float4*)dst0)[0] = make_float4(acc0[0], acc0[1], acc0[2], acc0[3]);
  ((float4*)dst0)[1] = make_float4(acc0[4], acc0[5], acc0[6], acc0[7]);
  ((float4*)dst1)[0] = make_float4(acc1[0], acc1[1], acc1[2], acc1[3]);
  ((float4*)dst1)[1] = make_float4(acc1[4], acc1[5], acc1[6], acc1[7]);
}

// ---------------------------------------------------------------------------
// B4: proto = sum of 8 partials; proto_sq; proto_h = bf16(proto).
// grid 512, block 256
// ---------------------------------------------------------------------------
__global__ __launch_bounds__(256) void k_red8sq(const float* __restrict__ part,
                                                float* __restrict__ proto,
                                                float* __restrict__ psq,
                                                short* __restrict__ Ph) {
  int g = blockIdx.x * 256 + threadIdx.x;
  float v = 0.f;
#pragma unroll
  for (int s = 0; s < FS2; ++s)
    v += part[(size_t)s * (BS * E_DIM * P_DIM) + g];
  proto[g] = v;
  Ph[g] = (short)f2bf(v);
  float q = v * v;
#pragma unroll
  for (int m = 1; m <= 16; m <<= 1) q += __shfl_xor(q, m, 64);
  if ((threadIdx.x & 31) == 0) psq[g >> 5] = q;
}

// ---------------------------------------------------------------------------
// C1: SCREENING chunk-max via bf16 MFMA (approximate; k_sparse's widened
// threshold absorbs the error — exact fp32 logit path unchanged).
// grid 2048, block 256 (4 waves x 16e). Operands from L2. No LDS.
// ---------------------------------------------------------------------------
__global__ __launch_bounds__(256) void k_gmax_mfma(
    const short* __restrict__ Kh, const float* __restrict__ Ksq,
    const short* __restrict__ Ph, float* __restrict__ chunkg) {
  const int tid = threadIdx.x;
  const int lane = tid & 63;
  const int w = tid >> 6;
  const int b = blockIdx.x >> 10;
  const int et = (blockIdx.x >> 5) & 31;
  const int ch = blockIdx.x & 31;
  const int e0 = (et << 6) + (w << 4);
  const int n0 = ch << 7;

  const int r15 = lane & 15, q = lane >> 4;

  short8 fa =
      *(const short8*)&Ph[((size_t)(b * E_DIM + e0 + r15)) * P_DIM + q * 8];

  f32x4 z = {0.f, 0.f, 0.f, 0.f};
  f32x4 ac0 = z, ac1 = z, ac2 = z, ac3 = z, ac4 = z, ac5 = z, ac6 = z, ac7 = z;
  const short* kb = Kh + ((size_t)(b * N_DIM + n0 + r15)) * P_DIM + q * 8;
#define GSTEP(S, AC)                                                     \
  {                                                                      \
    short8 fb = *(const short8*)(kb + (size_t)(S * 16) * P_DIM);         \
    AC = __builtin_amdgcn_mfma_f32_16x16x32_bf16(fa, fb, AC, 0, 0, 0);   \
  }
  GSTEP(0, ac0) GSTEP(1, ac1) GSTEP(2, ac2) GSTEP(3, ac3)
  GSTEP(4, ac4) GSTEP(5, ac5) GSTEP(6, ac6) GSTEP(7, ac7)
#undef GSTEP

  const float* qsb = Ksq + (size_t)b * N_DIM + n0 + r15;
  float ks0 = qsb[0], ks1 = qsb[16], ks2 = qsb[32], ks3 = qsb[48];
  float ks4 = qsb[64], ks5 = qsb[80], ks6 = qsb[96], ks7 = qsb[112];

#pragma unroll
  for (int r = 0; r < 4; ++r) {
    float m = fmaf(2.0f, ac0[r], -ks0);
    m = fmaxf(m, fmaf(2.0f, ac1[r], -ks1));
    m = fmaxf(m, fmaf(2.0f, ac2[r], -ks2));
    m = fmaxf(m, fmaf(2.0f, ac3[r], -ks3));
    m = fmaxf(m, fmaf(2.0f, ac4[r], -ks4));
    m = fmaxf(m, fmaf(2.0f, ac5[r], -ks5));
    m = fmaxf(m, fmaf(2.0f, ac6[r], -ks6));
    m = fmaxf(m, fmaf(2.0f, ac7[r], -ks7));
    m = fmaxf(m, __shfl_xor(m, 1, 64));
    m = fmaxf(m, __shfl_xor(m, 2, 64));
    m = fmaxf(m, __shfl_xor(m, 4, 64));
    m = fmaxf(m, __shfl_xor(m, 8, 64));
    if (r15 == 0)
      chunkg[((size_t)(b * E_DIM + e0 + q * 4 + r)) * 32 + ch] = m;
  }
}

// ---------------------------------------------------------------------------
// C2: per-edge sparse softmax-aggregate. One wave per edge.
// grid 1024, block 256 (4 waves). Screen threshold 3000 g-units.
// ---------------------------------------------------------------------------
__device__ __forceinline__ float edge_logit(const float* __restrict__ Kb,
                                            const float* __restrict__ Qb,
                                            const float* pr, float psqv,
                                            int n) {
  const float4* kp = (const float4*)(Kb + (size_t)n * P_DIM);
  float i0 = 0.f, i1 = 0.f, i2 = 0.f, i3 = 0.f;
#pragma unroll
  for (int q = 0; q < 8; ++q) {
    float4 kv = kp[q];
    i0 = fmaf(pr[4 * q + 0], kv.x, i0);
    i1 = fmaf(pr[4 * q + 1], kv.y, i1);
    i2 = fmaf(pr[4 * q + 2], kv.z, i2);
    i3 = fmaf(pr[4 * q + 3], kv.w, i3);
  }
  float inner = (i0 + i1) + (i2 + i3);
  float cost = fmaf(-2.0f, inner, psqv + Qb[n]);
  const float tau_eps = 0.1f + 1e-8f;
  return (-cost) / tau_eps;
}

__global__ __launch_bounds__(256) void k_sparse(
    const float* __restrict__ Kf, const float* __restrict__ Ksq,
    const float* __restrict__ proto, const float* __restrict__ psq,
    const float* __restrict__ VT, const float* __restrict__ chunkg,
    float* __restrict__ EF0) {
  const int tid = threadIdx.x;
  const int lane = tid & 63;
  const int eg = blockIdx.x * 4 + (tid >> 6);
  const int b = eg >> 11;
  const float* Kb = Kf + (size_t)b * N_DIM * P_DIM;
  const float* Qb = Ksq + (size_t)b * N_DIM;

  float cg = (lane < 32) ? chunkg[(size_t)eg * 32 + lane] : -INFINITY;
  float gmax = cg;
#pragma unroll
  for (int m = 1; m <= 32; m <<= 1) gmax = fmaxf(gmax, __shfl_xor(gmax, m, 64));
  unsigned long long live = __ballot(cg > gmax - 3000.0f);

  float pr[P_DIM];
  const float* pe = proto + (size_t)eg * P_DIM;
#pragma unroll
  for (int p = 0; p < P_DIM; ++p) pr[p] = pe[p];
  const float psqv = psq[eg];

  float L = -INFINITY;
  unsigned long long m0 = live;
  while (m0) {
    int c = __ffsll(m0) - 1;
    m0 &= m0 - 1;
    int n = (c << 7) + lane;
    L = fmaxf(L, edge_logit(Kb, Qb, pr, psqv, n));
    L = fmaxf(L, edge_logit(Kb, Qb, pr, psqv, n + 64));
  }
#pragma unroll
  for (int m = 1; m <= 32; m <<= 1) L = fmaxf(L, __shfl_xor(L, m, 64));

  float4 acc = make_float4(0.f, 0.f, 0.f, 0.f);
  float sw = 0.f;
  const float* Vb = VT + (size_t)b * N_DIM * C_DIM;
  m0 = live;
  while (m0) {
    int c = __ffsll(m0) - 1;
    m0 &= m0 - 1;
#pragma unroll
    for (int h = 0; h < 2; ++h) {
      int n = (c << 7) + (h << 6) + lane;
      float l = edge_logit(Kb, Qb, pr, psqv, n);
      float d = l - L;
      float wgt = (d > -25.0f) ? expf(d) : 0.f;
      sw += wgt;
      unsigned long long hits = __ballot(wgt > 0.f);
      while (hits) {
        int src = __ffsll(hits) - 1;
        hits &= hits - 1;
        float wv = __shfl(wgt, src, 64);
        int nv = (c << 7) + (h << 6) + src;
        const float4 vrow =
            *(const float4*)(Vb + (size_t)nv * C_DIM + (lane << 2));
        acc.x = fmaf(wv, vrow.x, acc.x);
        acc.y = fmaf(wv, vrow.y, acc.y);
        acc.z = fmaf(wv, vrow.z, acc.z);
        acc.w = fmaf(wv, vrow.w, acc.w);
      }
    }
  }
#pragma unroll
  for (int m = 1; m <= 32; m <<= 1) sw += __shfl_xor(sw, m, 64);

  float* dst = EF0 + (size_t)eg * C_DIM + (lane << 2);
  *(float4*)dst =
      make_float4(acc.x / sw, acc.y / sw, acc.z / sw, acc.w / sw);
}

// ---------------------------------------------------------------------------
// C3: EF0t[b][c][f] = bf16(EF0[b][f][c]).  grid 256, block 256, 64x64 tiles
// ---------------------------------------------------------------------------
__global__ __launch_bounds__(256) void k_ef0t(const float* __restrict__ EF0,
                                              short* __restrict__ EF0t) {
  __shared__ short sh[64][72];
  const int tid = threadIdx.x;
  const int b = blockIdx.x >> 7;
  const int ft = (blockIdx.x >> 2) & 31;
  const int ct = blockIdx.x & 3;
  const int f0 = ft << 6, c0 = ct << 6;
#pragma unroll
  for (int i = 0; i < 4; ++i) {
    int idx = tid + i * 256;
    int f_l = idx >> 4, cc = idx & 15;
    float4 v =
        *(const float4*)&EF0[((size_t)(b * E_DIM + f0 + f_l)) * C_DIM + c0 +
                             cc * 4];
    sh[cc * 4 + 0][f_l] = (short)f2bf(v.x);
    sh[cc * 4 + 1][f_l] = (short)f2bf(v.y);
    sh[cc * 4 + 2][f_l] = (short)f2bf(v.z);
    sh[cc * 4 + 3][f_l] = (short)f2bf(v.w);
  }
  __syncthreads();
#pragma unroll
  for (int i = 0; i < 2; ++i) {
    int idx = tid + i * 256;
    int c_l = idx >> 3, ch = idx & 7;
    short8 v = *(const short8*)&sh[c_l][ch * 8];
    *(short8*)&EF0t[((size_t)(b * C_DIM + c0 + c_l)) * E_DIM + f0 + ch * 8] = v;
  }
}

// ---------------------------------------------------------------------------
// D: bf16 MFMA GEMM, full K, double-buffered LDS + reg prefetch.
// grid 256, block 256 (4 waves). Tile 64e x 64c, BK=64, wave quad 32x32.
// ---------------------------------------------------------------------------
__device__ __forceinline__ short8 lds_frag(const short* s, int row, int k) {
  int off = (((row << 6) + k) << 1) ^ ((row & 7) << 4);
  return *(const short8*)((const char*)s + off);
}
__device__ __forceinline__ void lds_put(short* s, int row, int k, short8 v) {
  int off = (((row << 6) + k) << 1) ^ ((row & 7) << 4);
  *(short8*)((char*)s + off) = v;
}

__global__ __launch_bounds__(256) void k_final_mfma(
    const short* __restrict__ Ah, const short* __restrict__ Bh,
    float* __restrict__ out) {
  __shared__ short As[2][64 * 64];
  __shared__ short Bs[2][64 * 64];
  __shared__ float Cs[64][68];

  const int tid = threadIdx.x;
  const int lane = tid & 63;
  const int w = tid >> 6;
  const int ct = blockIdx.x & 3;
  const int et = (blockIdx.x >> 2) & 31;
  const int b = blockIdx.x >> 7;
  const int e0 = et << 6, c0 = ct << 6;

  const int we = (w >> 1) << 5;
  const int wc = (w & 1) << 5;
  const int row = tid >> 2, ch = tid & 3;

  const short* gA = Ah + ((size_t)(b * E_DIM + e0 + row)) * E_DIM;
  const short* gB = Bh + ((size_t)(b * C_DIM + c0 + row)) * E_DIM;

  f32x4 z = {0.f, 0.f, 0.f, 0.f};
  f32x4 acc00 = z, acc01 = z, acc10 = z, acc11 = z;

  {
    const short8* pa = (const short8*)(gA + ch * 16);
    const short8* pb = (const short8*)(gB + ch * 16);
    short8 a0 = pa[0], a1 = pa[1];
    short8 b0 = pb[0], b1 = pb[1];
    lds_put(As[0], row, ch * 16, a0);
    lds_put(As[0], row, ch * 16 + 8, a1);
    lds_put(Bs[0], row, ch * 16, b0);
    lds_put(Bs[0], row, ch * 16 + 8, b1);
  }
  __syncthreads();

  for (int kt = 0; kt < 32; ++kt) {
    const int cur = kt & 1;
    short8 na0, na1, nb0, nb1;
    if (kt < 31) {
      const int f1 = (kt + 1) << 6;
      const short8* pa = (const short8*)(gA + f1 + ch * 16);
      const short8* pb = (const short8*)(gB + f1 + ch * 16);
      na0 = pa[0]; na1 = pa[1]; nb0 = pb[0]; nb1 = pb[1];
    }
#pragma unroll
    for (int s = 0; s < 2; ++s) {
      const int kb = (s << 5) + ((lane >> 4) << 3);
      short8 fa0 = lds_frag(As[cur], we + (lane & 15), kb);
      short8 fa1 = lds_frag(As[cur], we + 16 + (lane & 15), kb);
      short8 fb0 = lds_frag(Bs[cur], wc + (lane & 15), kb);
      short8 fb1 = lds_frag(Bs[cur], wc + 16 + (lane & 15), kb);
      acc00 = __builtin_amdgcn_mfma_f32_16x16x32_bf16(fa0, fb0, acc00, 0, 0, 0);
      acc01 = __builtin_amdgcn_mfma_f32_16x16x32_bf16(fa0, fb1, acc01, 0, 0, 0);
      acc10 = __builtin_amdgcn_mfma_f32_16x16x32_bf16(fa1, fb0, acc10, 0, 0, 0);
      acc11 = __builtin_amdgcn_mfma_f32_16x16x32_bf16(fa1, fb1, acc11, 0, 0, 0);
    }
    if (kt < 31) {
      lds_put(As[cur ^ 1], row, ch * 16, na0);
      lds_put(As[cur ^ 1], row, ch * 16 + 8, na1);
      lds_put(Bs[cur ^ 1], row, ch * 16, nb0);
      lds_put(Bs[cur ^ 1], row, ch * 16 + 8, nb1);
    }
    __syncthreads();
  }

  const int fr = lane & 15, fq = lane >> 4;
#pragma unroll
  for (int r = 0; r < 4; ++r) {
    Cs[wc + fr][we + fq * 4 + r] = acc00[r];
    Cs[wc + 16 + fr][we + fq * 4 + r] = acc01[r];
    Cs[wc + fr][we + 16 + fq * 4 + r] = acc10[r];
    Cs[wc + 16 + fr][we + 16 + fq * 4 + r] = acc11[r];
  }
  __syncthreads();
  {
    const int c_l = tid >> 2, cch = tid & 3;
    float* dst = out + ((size_t)(b * C_DIM + c0 + c_l)) * E_DIM + e0;
#pragma unroll
    for (int r = 0; r < 4; ++r) {
      float4 v = *(const float4*)&Cs[c_l][cch * 16 + r * 4];
      *(float4*)&dst[cch * 16 + r * 4] = v;
    }
  }
}

// ---------------------------------------------------------------------------
extern "C" void kernel_launch(void* const* d_in, const int* in_sizes, int n_in,
                              void* d_out, int out_size, void* d_ws,
                              size_t ws_size, hipStream_t stream) {
  (void)in_sizes; (void)n_in; (void)out_size; (void)ws_size;
  const float* vf  = (const float*)d_in[0];
  const float* inc = (const float*)d_in[1];
  const float* ied = (const float*)d_in[2];
  const float* pw  = (const float*)d_in[5];
  const float* gm  = (const float*)d_in[6];
  const float* bt  = (const float*)d_in[7];
  const float* mn  = (const float*)d_in[8];
  const float* vr  = (const float*)d_in[9];
  float* out = (float*)d_out;

  float* ws = (float*)d_ws;
  float* VT      = ws;                  // 2,097,152 f
  float* Kf      = VT + 2097152;        //   262,144
  float* Ksq     = Kf + 262144;         //     8,192
  float* proto1  = Ksq + 8192;          //   131,072
  float* proto   = proto1 + 131072;     //   131,072
  float* psq     = proto + 131072;      //     4,096
  float* P1p     = psq + 4096;          // 32*131,072 = 4,194,304
  float* P2p     = P1p + 4194304;       //  8*131,072 = 1,048,576
  float* EF0     = P2p + 1048576;       // 1,048,576
  float* chunkg  = EF0 + 1048576;       //   131,072
  short* ied_h   = (short*)(chunkg + 131072);            // 8,388,608 shorts
  short* EF0t    = (short*)(chunkg + 131072 + 4194304);  // 1,048,576 shorts
  short* Kh      = EF0t + 1048576;                       //   262,144 shorts
  short* Ph      = Kh + 262144;                          //   131,072 shorts
  // total ~48 MB

  k_proj<<<dim3(128), dim3(256), 0, stream>>>(vf, pw, gm, bt, mn, vr, Kf, Ksq,
                                              Kh, VT);
  k_proto1<<<dim3(256), dim3(256), 0, stream>>>(inc, Kf, P1p);
  k_red32<<<dim3(512), dim3(256), 0, stream>>>(P1p, proto1);
  k_proto2<<<dim3(256), dim3(256), 0, stream>>>(ied, proto1, P2p, ied_h);
  k_red8sq<<<dim3(512), dim3(256), 0, stream>>>(P2p, proto, psq, Ph);
  k_gmax_mfma<<<dim3(2048), dim3(256), 0, stream>>>(Kh, Ksq, Ph, chunkg);
  k_sparse<<<dim3(1024), dim3(256), 0, stream>>>(Kf, Ksq, proto, psq, VT,
                                                 chunkg, EF0);
  k_ef0t<<<dim3(256), dim3(256), 0, stream>>>(EF0, EF0t);
  k_final_mfma<<<dim3(256), dim3(256), 0, stream>>>(ied_h, EF0t, out);
}

// Round 14
// 126.838 us; speedup vs baseline: 1.6232x; 1.0493x over previous
//
#include <hip/hip_runtime.h>
#include <math.h>

#define BS 2
#define C_DIM 256
#define N_DIM 4096
#define E_DIM 2048
#define P_DIM 32
#define NS1 32   // n-splits for proto1
#define FS2 8    // f-splits for proto2

typedef __attribute__((ext_vector_type(8))) short short8;
typedef __attribute__((ext_vector_type(4))) float f32x4;

__device__ __forceinline__ unsigned short f2bf(float f) {
  unsigned u = __float_as_uint(f);
  return (unsigned short)((u + 0x7FFFu + ((u >> 16) & 1u)) >> 16);
}

// ---------------------------------------------------------------------------
// A: K = BN(proj_w @ vf), Ksq, Kh = bf16(K), AND VT[b][n][c] = vf[b][c][n]
// (transpose fused: vf slice is L2-hot after phase 1).  grid 128, block 256
// ---------------------------------------------------------------------------
__global__ __launch_bounds__(256) void k_proj(
    const float* __restrict__ vf, const float* __restrict__ pw,
    const float* __restrict__ gamma, const float* __restrict__ beta,
    const float* __restrict__ mean, const float* __restrict__ var,
    float* __restrict__ Kf, float* __restrict__ Ksq,
    short* __restrict__ Kh, float* __restrict__ VT) {
  __shared__ float w_s[P_DIM * C_DIM];
  __shared__ float part_s[4][64][P_DIM + 1];
  __shared__ float kt_s[64][P_DIM + 1];
  __shared__ float t2_s[64][65];
  __shared__ float sc_s[P_DIM], sb_s[P_DIM], sm_s[P_DIM];

  const int tid = threadIdx.x;
  const int b = blockIdx.x >> 6;
  const int n0 = (blockIdx.x & 63) << 6;

  for (int i = tid; i < P_DIM * C_DIM; i += 256) w_s[i] = pw[i];
  if (tid < P_DIM) {
    sc_s[tid] = gamma[tid] / sqrtf(var[tid] + 1e-5f);
    sb_s[tid] = beta[tid];
    sm_s[tid] = mean[tid];
  }
  __syncthreads();

  const int nl = tid & 63, cs = tid >> 6;
  const float* vbase = vf + (size_t)b * C_DIM * N_DIM + n0 + nl;
  float acc[P_DIM];
#pragma unroll
  for (int p = 0; p < P_DIM; ++p) acc[p] = 0.f;
#pragma unroll 4
  for (int cc = 0; cc < 64; ++cc) {
    int c = cs * 64 + cc;
    float v = vbase[(size_t)c * N_DIM];
    const float* wc = &w_s[c];
#pragma unroll
    for (int p = 0; p < P_DIM; ++p) acc[p] = fmaf(wc[p * C_DIM], v, acc[p]);
  }
#pragma unroll
  for (int p = 0; p < P_DIM; ++p) part_s[cs][nl][p] = acc[p];
  __syncthreads();

  for (int i = tid; i < 64 * P_DIM; i += 256) {
    int n_l = i >> 5, p = i & 31;
    float s = ((part_s[0][n_l][p] + part_s[1][n_l][p]) + part_s[2][n_l][p]) +
              part_s[3][n_l][p];
    float k = (s - sm_s[p]) * sc_s[p] + sb_s[p];
    size_t gi = ((size_t)(b * N_DIM + n0 + n_l)) * P_DIM + p;
    Kf[gi] = k;
    Kh[gi] = (short)f2bf(k);
    kt_s[n_l][p] = k;
  }
  __syncthreads();
  if (tid < 64) {
    float q = 0.f;
#pragma unroll
    for (int p = 0; p < P_DIM; ++p) q = fmaf(kt_s[tid][p], kt_s[tid][p], q);
    Ksq[b * N_DIM + n0 + tid] = q;
  }

  // ---- phase 2: transpose this block's 64-n strip of vf into VT (L2-hot)
  const float* src = vf + (size_t)b * C_DIM * N_DIM;
  float* dst = VT + (size_t)b * N_DIM * C_DIM;
  for (int ct = 0; ct < 4; ++ct) {
    const int c0 = ct << 6;
    __syncthreads();
#pragma unroll
    for (int i = 0; i < 16; ++i) {
      int idx = tid + i * 256;
      int c_l = idx >> 6, n_l2 = idx & 63;
      t2_s[c_l][n_l2] = src[(size_t)(c0 + c_l) * N_DIM + n0 + n_l2];
    }
    __syncthreads();
#pragma unroll
    for (int i = 0; i < 16; ++i) {
      int idx = tid + i * 256;
      int c_l = idx & 63, n_l2 = idx >> 6;
      dst[(size_t)(n0 + n_l2) * C_DIM + c0 + c_l] = t2_s[c_l][n_l2];
    }
  }
}

// ---------------------------------------------------------------------------
// B1: P1part[ns][b][e][p] = sum_{n in 128-chunk} inc[b][n][e]*K[b][n][p]
// grid 256 (= bs * 4 etiles(512e) * 32 nsplits), block 256, 2 e per thread.
// ---------------------------------------------------------------------------
__global__ __launch_bounds__(256) void k_proto1(const float* __restrict__ inc,
                                                const float* __restrict__ Kf,
                                                float* __restrict__ part) {
  __shared__ float k_s[64][P_DIM];
  const int tid = threadIdx.x;
  const int b = blockIdx.x >> 7;
  const int et = (blockIdx.x >> 5) & 3;
  const int ns = blockIdx.x & 31;
  const int e0 = et << 9;
  const int nbase = ns << 7;

  float acc0[P_DIM], acc1[P_DIM];
#pragma unroll
  for (int p = 0; p < P_DIM; ++p) { acc0[p] = 0.f; acc1[p] = 0.f; }

  for (int nt = 0; nt < 2; ++nt) {
    int n0 = nbase + nt * 64;
#pragma unroll
    for (int i = 0; i < 8; ++i) {
      int idx = tid + i * 256;
      ((float*)k_s)[idx] = Kf[((size_t)(b * N_DIM + n0)) * P_DIM + idx];
    }
    __syncthreads();
#pragma unroll 8
    for (int nn = 0; nn < 64; ++nn) {
      const float* irow = inc + ((size_t)(b * N_DIM + n0 + nn)) * E_DIM + e0;
      float va = irow[tid];
      float vb = irow[tid + 256];
      const float4* kv4 = (const float4*)k_s[nn];
#pragma unroll
      for (int q = 0; q < 8; ++q) {
        float4 kv = kv4[q];
        acc0[4 * q + 0] = fmaf(va, kv.x, acc0[4 * q + 0]);
        acc0[4 * q + 1] = fmaf(va, kv.y, acc0[4 * q + 1]);
        acc0[4 * q + 2] = fmaf(va, kv.z, acc0[4 * q + 2]);
        acc0[4 * q + 3] = fmaf(va, kv.w, acc0[4 * q + 3]);
        acc1[4 * q + 0] = fmaf(vb, kv.x, acc1[4 * q + 0]);
        acc1[4 * q + 1] = fmaf(vb, kv.y, acc1[4 * q + 1]);
        acc1[4 * q + 2] = fmaf(vb, kv.z, acc1[4 * q + 2]);
        acc1[4 * q + 3] = fmaf(vb, kv.w, acc1[4 * q + 3]);
      }
    }
    __syncthreads();
  }
  float* dst0 = part + (size_t)ns * (BS * E_DIM * P_DIM) +
                ((size_t)(b * E_DIM + e0 + tid)) * P_DIM;
  float* dst1 = dst0 + 256 * P_DIM;
#pragma unroll
  for (int q = 0; q < 8; ++q) {
    ((float4*)dst0)[q] = make_float4(acc0[4 * q + 0], acc0[4 * q + 1],
                                     acc0[4 * q + 2], acc0[4 * q + 3]);
    ((float4*)dst1)[q] = make_float4(acc1[4 * q + 0], acc1[4 * q + 1],
                                     acc1[4 * q + 2], acc1[4 * q + 3]);
  }
}

// ---------------------------------------------------------------------------
// B2: proto1 = sum of 32 partials.  grid 512, block 256
// ---------------------------------------------------------------------------
__global__ __launch_bounds__(256) void k_red32(const float* __restrict__ part,
                                               float* __restrict__ outp) {
  int g = blockIdx.x * 256 + threadIdx.x;
  float v = 0.f;
#pragma unroll
  for (int s = 0; s < NS1; ++s)
    v += part[(size_t)s * (BS * E_DIM * P_DIM) + g];
  outp[g] = v;
}

// ---------------------------------------------------------------------------
// B3: P2part[fs][b][e][p] = sum_{f in 256-chunk} ied[b][e][f]*proto1[b][f][p]
// grid 256, block 256, [2e][8p]/thread. ALSO emits ied_h = bf16(ied).
// ---------------------------------------------------------------------------
__global__ __launch_bounds__(256) void k_proto2(const float* __restrict__ ied,
                                                const float* __restrict__ proto1,
                                                float* __restrict__ part,
                                                short* __restrict__ ied_h) {
  __shared__ float inv_s[128][33];
  __shared__ float p1_s[32][P_DIM];
  const int tid = threadIdx.x;
  const int b = blockIdx.x >> 7;
  const int et = (blockIdx.x >> 3) & 15;
  const int fs = blockIdx.x & 7;
  const int e0 = et << 7;
  const int fbase = fs << 8;
  const int e_l = tid & 63, pg = tid >> 6;

  float acc0[8], acc1[8];
#pragma unroll
  for (int q = 0; q < 8; ++q) { acc0[q] = 0.f; acc1[q] = 0.f; }

  for (int ft = 0; ft < 8; ++ft) {
    int f0 = fbase + ft * 32;
    __syncthreads();
#pragma unroll
    for (int i = 0; i < 16; ++i) {
      int idx = tid + i * 256;
      int e_r = idx >> 5, f_l = idx & 31;
      size_t gidx = ((size_t)(b * E_DIM + e0 + e_r)) * E_DIM + f0 + f_l;
      float v = ied[gidx];
      inv_s[e_r][f_l] = v;
      ied_h[gidx] = (short)f2bf(v);
    }
#pragma unroll
    for (int i = 0; i < 4; ++i) {
      int idx = tid + i * 256;
      ((float*)p1_s)[idx] = proto1[((size_t)(b * E_DIM + f0)) * P_DIM + idx];
    }
    __syncthreads();
#pragma unroll
    for (int ff = 0; ff < 32; ++ff) {
      float a0 = inv_s[e_l][ff];
      float a1 = inv_s[e_l + 64][ff];
      const float4* pv4 = (const float4*)&p1_s[ff][pg * 8];
      float4 pv0 = pv4[0], pv1 = pv4[1];
      acc0[0] = fmaf(a0, pv0.x, acc0[0]);
      acc0[1] = fmaf(a0, pv0.y, acc0[1]);
      acc0[2] = fmaf(a0, pv0.z, acc0[2]);
      acc0[3] = fmaf(a0, pv0.w, acc0[3]);
      acc0[4] = fmaf(a0, pv1.x, acc0[4]);
      acc0[5] = fmaf(a0, pv1.y, acc0[5]);
      acc0[6] = fmaf(a0, pv1.z, acc0[6]);
      acc0[7] = fmaf(a0, pv1.w, acc0[7]);
      acc1[0] = fmaf(a1, pv0.x, acc1[0]);
      acc1[1] = fmaf(a1, pv0.y, acc1[1]);
      acc1[2] = fmaf(a1, pv0.z, acc1[2]);
      acc1[3] = fmaf(a1, pv0.w, acc1[3]);
      acc1[4] = fmaf(a1, pv1.x, acc1[4]);
      acc1[5] = fmaf(a1, pv1.y, acc1[5]);
      acc1[6] = fmaf(a1, pv1.z, acc1[6]);
      acc1[7] = fmaf(a1, pv1.w, acc1[7]);
    }
  }
  float* dst0 = part + (size_t)fs * (BS * E_DIM * P_DIM) +
                ((size_t)(b * E_DIM + e0 + e_l)) * P_DIM + pg * 8;
  float* dst1 = dst0 + 64 * P_DIM;
  ((float4*)dst0)[0] = make_float4(acc0[0], acc0[1], acc0[2], acc0[3]);
  ((float4*)dst0)[1] = make_float4(acc0[4], acc0[5], acc0[6], acc0[7]);
  ((float4*)dst1)[0] = make_float4(acc1[0], acc1[1], acc1[2], acc1[3]);
  ((float4*)dst1)[1] = make_float4(acc1[4], acc1[5], acc1[6], acc1[7]);
}

// ---------------------------------------------------------------------------
// B4: proto = sum of 8 partials; proto_sq; proto_h = bf16(proto).
// grid 512, block 256
// ---------------------------------------------------------------------------
__global__ __launch_bounds__(256) void k_red8sq(const float* __restrict__ part,
                                                float* __restrict__ proto,
                                                float* __restrict__ psq,
                                                short* __restrict__ Ph) {
  int g = blockIdx.x * 256 + threadIdx.x;
  float v = 0.f;
#pragma unroll
  for (int s = 0; s < FS2; ++s)
    v += part[(size_t)s * (BS * E_DIM * P_DIM) + g];
  proto[g] = v;
  Ph[g] = (short)f2bf(v);
  float q = v * v;
#pragma unroll
  for (int m = 1; m <= 16; m <<= 1) q += __shfl_xor(q, m, 64);
  if ((threadIdx.x & 31) == 0) psq[g >> 5] = q;
}

// ---------------------------------------------------------------------------
// C1: SCREENING chunk-max via bf16 MFMA (approximate; k_sparse's widened
// threshold absorbs the error — exact fp32 logit path unchanged).
// grid 2048, block 256 (4 waves x 16e). Operands from L2. No LDS.
// ---------------------------------------------------------------------------
__global__ __launch_bounds__(256) void k_gmax_mfma(
    const short* __restrict__ Kh, const float* __restrict__ Ksq,
    const short* __restrict__ Ph, float* __restrict__ chunkg) {
  const int tid = threadIdx.x;
  const int lane = tid & 63;
  const int w = tid >> 6;
  const int b = blockIdx.x >> 10;
  const int et = (blockIdx.x >> 5) & 31;
  const int ch = blockIdx.x & 31;
  const int e0 = (et << 6) + (w << 4);
  const int n0 = ch << 7;

  const int r15 = lane & 15, q = lane >> 4;

  short8 fa =
      *(const short8*)&Ph[((size_t)(b * E_DIM + e0 + r15)) * P_DIM + q * 8];

  f32x4 z = {0.f, 0.f, 0.f, 0.f};
  f32x4 ac0 = z, ac1 = z, ac2 = z, ac3 = z, ac4 = z, ac5 = z, ac6 = z, ac7 = z;
  const short* kb = Kh + ((size_t)(b * N_DIM + n0 + r15)) * P_DIM + q * 8;
#define GSTEP(S, AC)                                                     \
  {                                                                      \
    short8 fb = *(const short8*)(kb + (size_t)(S * 16) * P_DIM);         \
    AC = __builtin_amdgcn_mfma_f32_16x16x32_bf16(fa, fb, AC, 0, 0, 0);   \
  }
  GSTEP(0, ac0) GSTEP(1, ac1) GSTEP(2, ac2) GSTEP(3, ac3)
  GSTEP(4, ac4) GSTEP(5, ac5) GSTEP(6, ac6) GSTEP(7, ac7)
#undef GSTEP

  const float* qsb = Ksq + (size_t)b * N_DIM + n0 + r15;
  float ks0 = qsb[0], ks1 = qsb[16], ks2 = qsb[32], ks3 = qsb[48];
  float ks4 = qsb[64], ks5 = qsb[80], ks6 = qsb[96], ks7 = qsb[112];

#pragma unroll
  for (int r = 0; r < 4; ++r) {
    float m = fmaf(2.0f, ac0[r], -ks0);
    m = fmaxf(m, fmaf(2.0f, ac1[r], -ks1));
    m = fmaxf(m, fmaf(2.0f, ac2[r], -ks2));
    m = fmaxf(m, fmaf(2.0f, ac3[r], -ks3));
    m = fmaxf(m, fmaf(2.0f, ac4[r], -ks4));
    m = fmaxf(m, fmaf(2.0f, ac5[r], -ks5));
    m = fmaxf(m, fmaf(2.0f, ac6[r], -ks6));
    m = fmaxf(m, fmaf(2.0f, ac7[r], -ks7));
    m = fmaxf(m, __shfl_xor(m, 1, 64));
    m = fmaxf(m, __shfl_xor(m, 2, 64));
    m = fmaxf(m, __shfl_xor(m, 4, 64));
    m = fmaxf(m, __shfl_xor(m, 8, 64));
    if (r15 == 0)
      chunkg[((size_t)(b * E_DIM + e0 + q * 4 + r)) * 32 + ch] = m;
  }
}

// ---------------------------------------------------------------------------
// C2: per-edge sparse softmax-aggregate, SINGLE PASS (online max).
// One wave per edge. grid 1024, block 256 (4 waves). Threshold 3000 g-units.
// Logits computed once; acc/sw rescaled by exp(M_old-M_new) when the running
// max advances (wave-uniform). Final M equals the two-pass L exactly.
// ---------------------------------------------------------------------------
__device__ __forceinline__ float edge_logit(const float* __restrict__ Kb,
                                            const float* __restrict__ Qb,
                                            const float* pr, float psqv,
                                            int n) {
  const float4* kp = (const float4*)(Kb + (size_t)n * P_DIM);
  float i0 = 0.f, i1 = 0.f, i2 = 0.f, i3 = 0.f;
#pragma unroll
  for (int q = 0; q < 8; ++q) {
    float4 kv = kp[q];
    i0 = fmaf(pr[4 * q + 0], kv.x, i0);
    i1 = fmaf(pr[4 * q + 1], kv.y, i1);
    i2 = fmaf(pr[4 * q + 2], kv.z, i2);
    i3 = fmaf(pr[4 * q + 3], kv.w, i3);
  }
  float inner = (i0 + i1) + (i2 + i3);
  float cost = fmaf(-2.0f, inner, psqv + Qb[n]);
  const float tau_eps = 0.1f + 1e-8f;
  return (-cost) / tau_eps;
}

__global__ __launch_bounds__(256) void k_sparse(
    const float* __restrict__ Kf, const float* __restrict__ Ksq,
    const float* __restrict__ proto, const float* __restrict__ psq,
    const float* __restrict__ VT, const float* __restrict__ chunkg,
    float* __restrict__ EF0) {
  const int tid = threadIdx.x;
  const int lane = tid & 63;
  const int eg = blockIdx.x * 4 + (tid >> 6);
  const int b = eg >> 11;
  const float* Kb = Kf + (size_t)b * N_DIM * P_DIM;
  const float* Qb = Ksq + (size_t)b * N_DIM;

  float cg = (lane < 32) ? chunkg[(size_t)eg * 32 + lane] : -INFINITY;
  float gmax = cg;
#pragma unroll
  for (int m = 1; m <= 32; m <<= 1) gmax = fmaxf(gmax, __shfl_xor(gmax, m, 64));
  unsigned long long live = __ballot(cg > gmax - 3000.0f);

  float pr[P_DIM];
  const float* pe = proto + (size_t)eg * P_DIM;
#pragma unroll
  for (int p = 0; p < P_DIM; ++p) pr[p] = pe[p];
  const float psqv = psq[eg];

  float M = -INFINITY;
  float4 acc = make_float4(0.f, 0.f, 0.f, 0.f);
  float sw = 0.f;
  const float* Vb = VT + (size_t)b * N_DIM * C_DIM;

  unsigned long long m0 = live;
  while (m0) {
    int c = __ffsll(m0) - 1;
    m0 &= m0 - 1;
#pragma unroll
    for (int h = 0; h < 2; ++h) {
      int n = (c << 7) + (h << 6) + lane;
      float l = edge_logit(Kb, Qb, pr, psqv, n);
      // wave max of this 64-n group
      float ml = l;
      ml = fmaxf(ml, __shfl_xor(ml, 1, 64));
      ml = fmaxf(ml, __shfl_xor(ml, 2, 64));
      ml = fmaxf(ml, __shfl_xor(ml, 4, 64));
      ml = fmaxf(ml, __shfl_xor(ml, 8, 64));
      ml = fmaxf(ml, __shfl_xor(ml, 16, 64));
      ml = fmaxf(ml, __shfl_xor(ml, 32, 64));
      if (ml > M) {  // wave-uniform rescale
        float scale = expf(M - ml);  // first time: exp(-inf)=0 on zero accs
        acc.x *= scale; acc.y *= scale; acc.z *= scale; acc.w *= scale;
        sw *= scale;
        M = ml;
      }
      float d = l - M;
      float wgt = (d > -25.0f) ? expf(d) : 0.f;
      sw += wgt;
      unsigned long long hits = __ballot(wgt > 0.f);
      while (hits) {
        int src = __ffsll(hits) - 1;
        hits &= hits - 1;
        float wv = __shfl(wgt, src, 64);
        int nv = (c << 7) + (h << 6) + src;
        const float4 vrow =
            *(const float4*)(Vb + (size_t)nv * C_DIM + (lane << 2));
        acc.x = fmaf(wv, vrow.x, acc.x);
        acc.y = fmaf(wv, vrow.y, acc.y);
        acc.z = fmaf(wv, vrow.z, acc.z);
        acc.w = fmaf(wv, vrow.w, acc.w);
      }
    }
  }
#pragma unroll
  for (int m = 1; m <= 32; m <<= 1) sw += __shfl_xor(sw, m, 64);

  float* dst = EF0 + (size_t)eg * C_DIM + (lane << 2);
  *(float4*)dst =
      make_float4(acc.x / sw, acc.y / sw, acc.z / sw, acc.w / sw);
}

// ---------------------------------------------------------------------------
// C3: EF0t[b][c][f] = bf16(EF0[b][f][c]).  grid 256, block 256, 64x64 tiles
// ---------------------------------------------------------------------------
__global__ __launch_bounds__(256) void k_ef0t(const float* __restrict__ EF0,
                                              short* __restrict__ EF0t) {
  __shared__ short sh[64][72];
  const int tid = threadIdx.x;
  const int b = blockIdx.x >> 7;
  const int ft = (blockIdx.x >> 2) & 31;
  const int ct = blockIdx.x & 3;
  const int f0 = ft << 6, c0 = ct << 6;
#pragma unroll
  for (int i = 0; i < 4; ++i) {
    int idx = tid + i * 256;
    int f_l = idx >> 4, cc = idx & 15;
    float4 v =
        *(const float4*)&EF0[((size_t)(b * E_DIM + f0 + f_l)) * C_DIM + c0 +
                             cc * 4];
    sh[cc * 4 + 0][f_l] = (short)f2bf(v.x);
    sh[cc * 4 + 1][f_l] = (short)f2bf(v.y);
    sh[cc * 4 + 2][f_l] = (short)f2bf(v.z);
    sh[cc * 4 + 3][f_l] = (short)f2bf(v.w);
  }
  __syncthreads();
#pragma unroll
  for (int i = 0; i < 2; ++i) {
    int idx = tid + i * 256;
    int c_l = idx >> 3, ch = idx & 7;
    short8 v = *(const short8*)&sh[c_l][ch * 8];
    *(short8*)&EF0t[((size_t)(b * C_DIM + c0 + c_l)) * E_DIM + f0 + ch * 8] = v;
  }
}

// ---------------------------------------------------------------------------
// D: bf16 MFMA GEMM, full K, double-buffered LDS + reg prefetch.
// grid 256, block 256 (4 waves). Tile 64e x 64c, BK=64, wave quad 32x32.
// ---------------------------------------------------------------------------
__device__ __forceinline__ short8 lds_frag(const short* s, int row, int k) {
  int off = (((row << 6) + k) << 1) ^ ((row & 7) << 4);
  return *(const short8*)((const char*)s + off);
}
__device__ __forceinline__ void lds_put(short* s, int row, int k, short8 v) {
  int off = (((row << 6) + k) << 1) ^ ((row & 7) << 4);
  *(short8*)((char*)s + off) = v;
}

__global__ __launch_bounds__(256) void k_final_mfma(
    const short* __restrict__ Ah, const short* __restrict__ Bh,
    float* __restrict__ out) {
  __shared__ short As[2][64 * 64];
  __shared__ short Bs[2][64 * 64];
  __shared__ float Cs[64][68];

  const int tid = threadIdx.x;
  const int lane = tid & 63;
  const int w = tid >> 6;
  const int ct = blockIdx.x & 3;
  const int et = (blockIdx.x >> 2) & 31;
  const int b = blockIdx.x >> 7;
  const int e0 = et << 6, c0 = ct << 6;

  const int we = (w >> 1) << 5;
  const int wc = (w & 1) << 5;
  const int row = tid >> 2, ch = tid & 3;

  const short* gA = Ah + ((size_t)(b * E_DIM + e0 + row)) * E_DIM;
  const short* gB = Bh + ((size_t)(b * C_DIM + c0 + row)) * E_DIM;

  f32x4 z = {0.f, 0.f, 0.f, 0.f};
  f32x4 acc00 = z, acc01 = z, acc10 = z, acc11 = z;

  {
    const short8* pa = (const short8*)(gA + ch * 16);
    const short8* pb = (const short8*)(gB + ch * 16);
    short8 a0 = pa[0], a1 = pa[1];
    short8 b0 = pb[0], b1 = pb[1];
    lds_put(As[0], row, ch * 16, a0);
    lds_put(As[0], row, ch * 16 + 8, a1);
    lds_put(Bs[0], row, ch * 16, b0);
    lds_put(Bs[0], row, ch * 16 + 8, b1);
  }
  __syncthreads();

  for (int kt = 0; kt < 32; ++kt) {
    const int cur = kt & 1;
    short8 na0, na1, nb0, nb1;
    if (kt < 31) {
      const int f1 = (kt + 1) << 6;
      const short8* pa = (const short8*)(gA + f1 + ch * 16);
      const short8* pb = (const short8*)(gB + f1 + ch * 16);
      na0 = pa[0]; na1 = pa[1]; nb0 = pb[0]; nb1 = pb[1];
    }
#pragma unroll
    for (int s = 0; s < 2; ++s) {
      const int kb = (s << 5) + ((lane >> 4) << 3);
      short8 fa0 = lds_frag(As[cur], we + (lane & 15), kb);
      short8 fa1 = lds_frag(As[cur], we + 16 + (lane & 15), kb);
      short8 fb0 = lds_frag(Bs[cur], wc + (lane & 15), kb);
      short8 fb1 = lds_frag(Bs[cur], wc + 16 + (lane & 15), kb);
      acc00 = __builtin_amdgcn_mfma_f32_16x16x32_bf16(fa0, fb0, acc00, 0, 0, 0);
      acc01 = __builtin_amdgcn_mfma_f32_16x16x32_bf16(fa0, fb1, acc01, 0, 0, 0);
      acc10 = __builtin_amdgcn_mfma_f32_16x16x32_bf16(fa1, fb0, acc10, 0, 0, 0);
      acc11 = __builtin_amdgcn_mfma_f32_16x16x32_bf16(fa1, fb1, acc11, 0, 0, 0);
    }
    if (kt < 31) {
      lds_put(As[cur ^ 1], row, ch * 16, na0);
      lds_put(As[cur ^ 1], row, ch * 16 + 8, na1);
      lds_put(Bs[cur ^ 1], row, ch * 16, nb0);
      lds_put(Bs[cur ^ 1], row, ch * 16 + 8, nb1);
    }
    __syncthreads();
  }

  const int fr = lane & 15, fq = lane >> 4;
#pragma unroll
  for (int r = 0; r < 4; ++r) {
    Cs[wc + fr][we + fq * 4 + r] = acc00[r];
    Cs[wc + 16 + fr][we + fq * 4 + r] = acc01[r];
    Cs[wc + fr][we + 16 + fq * 4 + r] = acc10[r];
    Cs[wc + 16 + fr][we + 16 + fq * 4 + r] = acc11[r];
  }
  __syncthreads();
  {
    const int c_l = tid >> 2, cch = tid & 3;
    float* dst = out + ((size_t)(b * C_DIM + c0 + c_l)) * E_DIM + e0;
#pragma unroll
    for (int r = 0; r < 4; ++r) {
      float4 v = *(const float4*)&Cs[c_l][cch * 16 + r * 4];
      *(float4*)&dst[cch * 16 + r * 4] = v;
    }
  }
}

// ---------------------------------------------------------------------------
extern "C" void kernel_launch(void* const* d_in, const int* in_sizes, int n_in,
                              void* d_out, int out_size, void* d_ws,
                              size_t ws_size, hipStream_t stream) {
  (void)in_sizes; (void)n_in; (void)out_size; (void)ws_size;
  const float* vf  = (const float*)d_in[0];
  const float* inc = (const float*)d_in[1];
  const float* ied = (const float*)d_in[2];
  const float* pw  = (const float*)d_in[5];
  const float* gm  = (const float*)d_in[6];
  const float* bt  = (const float*)d_in[7];
  const float* mn  = (const float*)d_in[8];
  const float* vr  = (const float*)d_in[9];
  float* out = (float*)d_out;

  float* ws = (float*)d_ws;
  float* VT      = ws;                  // 2,097,152 f
  float* Kf      = VT + 2097152;        //   262,144
  float* Ksq     = Kf + 262144;         //     8,192
  float* proto1  = Ksq + 8192;          //   131,072
  float* proto   = proto1 + 131072;     //   131,072
  float* psq     = proto + 131072;      //     4,096
  float* P1p     = psq + 4096;          // 32*131,072 = 4,194,304
  float* P2p     = P1p + 4194304;       //  8*131,072 = 1,048,576
  float* EF0     = P2p + 1048576;       // 1,048,576
  float* chunkg  = EF0 + 1048576;       //   131,072
  short* ied_h   = (short*)(chunkg + 131072);            // 8,388,608 shorts
  short* EF0t    = (short*)(chunkg + 131072 + 4194304);  // 1,048,576 shorts
  short* Kh      = EF0t + 1048576;                       //   262,144 shorts
  short* Ph      = Kh + 262144;                          //   131,072 shorts
  // total ~48 MB

  k_proj<<<dim3(128), dim3(256), 0, stream>>>(vf, pw, gm, bt, mn, vr, Kf, Ksq,
                                              Kh, VT);
  k_proto1<<<dim3(256), dim3(256), 0, stream>>>(inc, Kf, P1p);
  k_red32<<<dim3(512), dim3(256), 0, stream>>>(P1p, proto1);
  k_proto2<<<dim3(256), dim3(256), 0, stream>>>(ied, proto1, P2p, ied_h);
  k_red8sq<<<dim3(512), dim3(256), 0, stream>>>(P2p, proto, psq, Ph);
  k_gmax_mfma<<<dim3(2048), dim3(256), 0, stream>>>(Kh, Ksq, Ph, chunkg);
  k_sparse<<<dim3(1024), dim3(256), 0, stream>>>(Kf, Ksq, proto, psq, VT,
                                                 chunkg, EF0);
  k_ef0t<<<dim3(256), dim3(256), 0, stream>>>(EF0, EF0t);
  k_final_mfma<<<dim3(256), dim3(256), 0, stream>>>(ied_h, EF0t, out);
}